// Round 10
// baseline (610.540 us; speedup 1.0000x reference)
//
#include <hip/hip_runtime.h>
#include <math.h>

typedef _Float16 f16;
typedef f16  f16x8 __attribute__((ext_vector_type(8)));
typedef float f32x4 __attribute__((ext_vector_type(4)));
typedef unsigned short ushort_t;

#define MFMA16(a, b, c) __builtin_amdgcn_mfma_f32_16x16x32_f16((a), (b), (c), 0, 0, 0)

// ---------------- workspace layout (f16 element offsets) ----------------
#define W1T_E 0        // [256][512]  vae_W1^T, K permuted to S2 order
#define WZV_E 131072   // [48][256]   [vae_Wz | vae_Wv | 0]^T
#define A1T_E 143360   // [64][96]    ae_W1^T
#define A2T_E 149504   // [32][64]    ae_W2^T
#define G1T_E 151552   // [64][32]    gate_W1^T
#define G2T_E 153600   // [16][64]    gate_W2^T (cols 5..15 zero)
#define E1T_E 154624   // [5][128][192] eW1^T, K remapped to padded-192 buf0 layout
#define E2T_E 277504   // [5][128][128] eW2^T
#define E3T_E 359424   // [5][32][128]  eW3^T, cols 29..31 zero
#define F32_B 759808   // f32 appendix: BZV[48] | EB3P[160] | GB2P[16]

// ---------------- LDS layout (bytes), 64-row tile, 2 blocks/CU ----------------
#define S2_OFF   0       // [64][488] f16; after G1: H[64][264]@0 + B0[64][200]@36864
#define B0_OFF   36864
#define H2_OFF   17408   // experts: H1@0, H2 here (both inside dead-S2 region)
#define ELEV_OFF 62528   // [64][104] f16 (64B pad at 62464 before it)
#define HA_OFF   62528   // [64][72] f16 (after G3; elev dead)
#define ZE_OFF   71744   // [64][40] f16 (stride 40: 2-way banks, was 8-way at 32)
#define WF_OFF   76864   // [64][12] f32 gate weights (stride 12: aligned + 2-way)
#define SMEM_SZ  79936   // 2 x 79936 <= 163840 -> 2 blocks/CU

__device__ __forceinline__ float elu_f(float v) {
    float e = __expf(v) - 1.f;
    return v > 0.f ? v : e;
}

// round-to-nearest f32x2 -> packed f16x2 (RTZ pkrtz biased the chain; keep RTN)
__device__ __forceinline__ unsigned pk(float a, float b) {
    ushort_t u0 = __builtin_bit_cast(ushort_t, (f16)a);
    ushort_t u1 = __builtin_bit_cast(ushort_t, (f16)b);
    return (unsigned)u0 | ((unsigned)u1 << 16);
}

__device__ __forceinline__ void store4(f16* p, f32x4 v) {
    uint2 t; t.x = pk(v[0], v[1]); t.y = pk(v[2], v[3]);
    *(uint2*)p = t;
}

__device__ __forceinline__ void elu_store4(f16* p, f32x4 v) {
    uint2 t; t.x = pk(elu_f(v[0]), elu_f(v[1])); t.y = pk(elu_f(v[2]), elu_f(v[3]));
    *(uint2*)p = t;
}

// LDS-only barrier: drains DS ops but leaves global loads in flight.
__device__ __forceinline__ void sync_lds() {
    asm volatile("s_waitcnt lgkmcnt(0)" ::: "memory");
    __builtin_amdgcn_s_barrier();
    asm volatile("" ::: "memory");
    __builtin_amdgcn_sched_barrier(0);
}

// ---------------- weight repack: fp32 -> f16, transposed/padded/permuted ----------------
__global__ void prep_kernel(const float* __restrict__ vW1, const float* __restrict__ vWz,
                            const float* __restrict__ vWv, const float* __restrict__ aW1,
                            const float* __restrict__ aW2, const float* __restrict__ gW1,
                            const float* __restrict__ gW2, const float* __restrict__ eW1,
                            const float* __restrict__ eW2, const float* __restrict__ eW3,
                            const float* __restrict__ vbz, const float* __restrict__ vbv,
                            const float* __restrict__ eb3, const float* __restrict__ gb2,
                            char* __restrict__ ws)
{
    int i = blockIdx.x * 256 + threadIdx.x;
    f16* H = (f16*)ws;
    if (i < 131072) {                                   // W1T [c=256][ks=512], S2-order K
        int c = i >> 9, ks = i & 511;
        int xcol = 12 + ks;
        float v = 0.f;
        if (xcol >= 15 && xcol <= 494) {
            int hc;
            if (xcol < 60) {
                int t = xcol / 15; int rm = xcol - 15 * t; int f = rm / 3;
                hc = 96 * f + 3 * (t - 1) + (rm - 3 * f);
            } else {
                int t2 = (xcol - 60) / 145; int rm = xcol - 60 - 145 * t2; int f = rm / 29;
                hc = 96 * f + 9 + 29 * t2 + (rm - 29 * f);
            }
            v = vW1[hc * 256 + c];
        }
        H[i] = (f16)v;
    } else if (i < 143360) {                            // WZV [c=48][k=256]
        int j = i - 131072; int c = j / 256, k = j - c * 256;
        float v = (c < 32) ? vWz[k * 32 + c] : ((c < 35) ? vWv[k * 3 + (c - 32)] : 0.f);
        H[i] = (f16)v;
    } else if (i < 149504) {                            // A1T [c=64][k=96]
        int j = i - 143360; int c = j / 96, k = j - c * 96;
        H[i] = (f16)aW1[k * 64 + c];
    } else if (i < 151552) {                            // A2T [c=32][k=64]
        int j = i - 149504; int c = j / 64, k = j - c * 64;
        H[i] = (f16)aW2[k * 32 + c];
    } else if (i < 153600) {                            // G1T [c=64][k=32]
        int j = i - 151552; int c = j / 32, k = j - c * 32;
        H[i] = (f16)gW1[k * 64 + c];
    } else if (i < 154624) {                            // G2T [c=16][k=64]
        int j = i - 153600; int c = j / 64, k = j - c * 64;
        H[i] = (f16)((c < 5) ? gW2[k * 5 + c] : 0.f);
    } else if (i < 277504) {                            // E1T [e][c=128][k=192] remapped
        int j = i - 154624; int e = j / 24576, jj = j - e * 24576;
        int c = jj / 192, k = jj - c * 192;
        int ko = (k >= 5 && k < 107)   ? (k - 5)
               : (k >= 108 && k < 140) ? (k - 6)
               : (k >= 144 && k < 176) ? (k - 10) : -1;
        H[i] = (f16)((ko >= 0) ? eW1[(e * 166 + ko) * 128 + c] : 0.f);
    } else if (i < 359424) {                            // E2T [e][c=128][k=128]
        int j = i - 277504; int e = j / 16384, jj = j - e * 16384;
        int c = jj / 128, k = jj - c * 128;
        H[i] = (f16)eW2[(e * 128 + k) * 128 + c];
    } else if (i < 379904) {                            // E3T [e][c=32][k=128]
        int j = i - 359424; int e = j / 4096, jj = j - e * 4096;
        int c = jj / 128, k = jj - c * 128;
        H[i] = (f16)((c < 29) ? eW3[(e * 128 + k) * 29 + c] : 0.f);
    } else if (i < 380128) {                            // f32 appendix
        int j = i - 379904;
        float* F = (float*)(ws + F32_B);
        float v;
        if (j < 48)       v = (j < 32) ? vbz[j] : ((j < 35) ? vbv[j - 32] : 0.f);
        else if (j < 208) { int t = j - 48; int e = t >> 5, c = t & 31;
                            v = (c < 29) ? eb3[e * 29 + c] : 0.f; }
        else              { int t = j - 208; v = (t < 5) ? gb2[t] : 0.f; }
        F[j] = v;
    }
}

// ---------------- fused actor: 64 rows/block, 512 threads, redundancy-2 tiling ----------------
__global__ __launch_bounds__(512, 4) void moe_fused(
    const float* __restrict__ x,
    const float* __restrict__ vb1,
    const float* __restrict__ ab1,
    const float* __restrict__ ab2,
    const float* __restrict__ gb1,
    const float* __restrict__ eb1,
    const float* __restrict__ eb2,
    const char* __restrict__ ws,
    float* __restrict__ out)
{
    __shared__ __align__(16) char smem[SMEM_SZ];
    const int tid  = threadIdx.x;
    const int wv   = tid >> 6;      // 0..7
    const int lane = tid & 63;
    const int lr   = lane & 15;
    const int lg   = lane >> 4;
    const int rh   = wv & 1;        // row half for G3/G1 (2 m-tiles each)
    const int cq   = wv >> 1;       // col quarter 0..3
    const int em   = wv & 3;        // expert phases: single m-tile per wave
    const int ecg  = wv >> 2;       // expert phases: col half 0..1
    const int row0 = (int)blockIdx.x * 64;

    const f16* W1T = (const f16*)ws + W1T_E;
    const f16* WZV = (const f16*)ws + WZV_E;
    const f16* A1T = (const f16*)ws + A1T_E;
    const f16* A2T = (const f16*)ws + A2T_E;
    const f16* G1T = (const f16*)ws + G1T_E;
    const f16* G2T = (const f16*)ws + G2T_E;
    const f16* E1T = (const f16*)ws + E1T_E;
    const f16* E2T = (const f16*)ws + E2T_E;
    const f16* E3T = (const f16*)ws + E3T_E;
    const float* BZV  = (const float*)(ws + F32_B);
    const float* EB3P = BZV + 48;
    const float* GB2P = BZV + 208;

    f16* sS2 = (f16*)(smem + S2_OFF);     // stride 488
    f16* sEl = (f16*)(smem + ELEV_OFF);   // stride 104
    f16* sHA = (f16*)(smem + HA_OFF);     // stride 72 (ha, then gh)
    f16* sZE = (f16*)(smem + ZE_OFF);     // stride 40
    f16* sH  = (f16*)(smem + S2_OFF);     // stride 264 (after G1)
    f16* sB0 = (f16*)(smem + B0_OFF);     // stride 200 (after G1)
    f16* sH1 = (f16*)(smem + S2_OFF);     // stride 136 (experts)
    f16* sH2 = (f16*)(smem + H2_OFF);     // stride 136
    float* sWf = (float*)(smem + WF_OFF); // stride 12 f32

    // ---- P0: coalesced staging of S2 + elev (8 rows per wave) ----
    {
        if (tid < 16) *(unsigned*)(smem + 62464 + 4 * tid) = 0u;  // S2 tail pad
        const int sr0 = wv * 8;
        for (int rr = 0; rr < 8; ++rr) {
            const int r = sr0 + rr;
            const float* xr = x + (size_t)(row0 + r) * 975;
            if (lane < 48) {
                float a = xr[879 + 2 * lane], b = xr[880 + 2 * lane];
                *(unsigned*)(sEl + r * 104 + 2 * lane) = pk(a, b);
            }
            f16* dst = sS2 + r * 488;
#pragma unroll
            for (int j = 0; j < 4; ++j) {
                int p = j * 64 + lane;
                if (p < 244) {
                    float a = 0.f, b = 0.f;
                    if (p < 242) { a = xr[12 + 2 * p]; b = xr[13 + 2 * p]; }
                    *(unsigned*)(dst + 2 * p) = pk(a, b);
                }
            }
        }
    }
    sync_lds();                                           // S1

    // ---- G3: ha = elu(e_t @ ae_W1 + ae_b1); 2 row-halves x 4 col-quarters ----
    f32x4 g3acc[2];
    {
        f32x4 bi = *(const f32x4*)(ab1 + 16 * cq + 4 * lg);
        g3acc[0] = bi; g3acc[1] = bi;
#pragma unroll
        for (int ks = 0; ks < 3; ++ks) {
            f16x8 wf = *(const f16x8*)(A1T + (16 * cq + lr) * 96 + 32 * ks + 8 * lg);
#pragma unroll
            for (int mm = 0; mm < 2; ++mm) {
                int m = 2 * rh + mm;
                f16x8 bf = *(const f16x8*)(sEl + (16 * m + lr) * 104 + 32 * ks + 8 * lg);
                g3acc[mm] = MFMA16(wf, bf, g3acc[mm]);
            }
        }
    }
    sync_lds();                                           // S2: elev reads done
#pragma unroll
    for (int mm = 0; mm < 2; ++mm)
        elu_store4(sHA + (16 * (2 * rh + mm) + lr) * 72 + 16 * cq + 4 * lg, g3acc[mm]);
    sync_lds();                                           // S3

    // ---- G4 (waves 0..3): z_E = ha @ ae_W2 + ae_b2 -> sZE ----
    if (wv < 4) {
        int c = wv >> 1, h = wv & 1;
        f32x4 bi = *(const f32x4*)(ab2 + 16 * c + 4 * lg);
        f32x4 acc[2]; acc[0] = bi; acc[1] = bi;
#pragma unroll
        for (int ks = 0; ks < 2; ++ks) {
            f16x8 wf = *(const f16x8*)(A2T + (16 * c + lr) * 64 + 32 * ks + 8 * lg);
#pragma unroll
            for (int mm = 0; mm < 2; ++mm) {
                int m = 2 * h + mm;
                f16x8 bf = *(const f16x8*)(sHA + (16 * m + lr) * 72 + 32 * ks + 8 * lg);
                acc[mm] = MFMA16(wf, bf, acc[mm]);
            }
        }
#pragma unroll
        for (int mm = 0; mm < 2; ++mm)
            store4(sZE + (16 * (2 * h + mm) + lr) * 40 + 16 * c + 4 * lg, acc[mm]);
    }
    sync_lds();                                           // S4

    // ---- gate hidden: gh = elu(z_E @ gate_W1 + gate_b1), K=32 -> sHA ----
    {
        f32x4 bi = *(const f32x4*)(gb1 + 16 * cq + 4 * lg);
        f32x4 acc[2]; acc[0] = bi; acc[1] = bi;
        f16x8 wf = *(const f16x8*)(G1T + (16 * cq + lr) * 32 + 8 * lg);
#pragma unroll
        for (int mm = 0; mm < 2; ++mm) {
            int m = 2 * rh + mm;
            f16x8 bf = *(const f16x8*)(sZE + (16 * m + lr) * 40 + 8 * lg);
            acc[mm] = MFMA16(wf, bf, acc[mm]);
        }
#pragma unroll
        for (int mm = 0; mm < 2; ++mm)
            elu_store4(sHA + (16 * (2 * rh + mm) + lr) * 72 + 16 * cq + 4 * lg, acc[mm]);
    }
    sync_lds();                                           // S5

    // ---- gate logits (wave 0) -> sWf ; guarded (R2/R3 OOB lesson) ----
    if (wv == 0) {
        f32x4 bi = *(const f32x4*)(GB2P + 4 * lg);
        f32x4 acc[4];
#pragma unroll
        for (int m = 0; m < 4; ++m) acc[m] = bi;
#pragma unroll
        for (int ks = 0; ks < 2; ++ks) {
            f16x8 wf = *(const f16x8*)(G2T + lr * 64 + 32 * ks + 8 * lg);
#pragma unroll
            for (int m = 0; m < 4; ++m) {
                f16x8 bf = *(const f16x8*)(sHA + (16 * m + lr) * 72 + 32 * ks + 8 * lg);
                acc[m] = MFMA16(wf, bf, acc[m]);
            }
        }
        if (lg == 0) {
#pragma unroll
            for (int m = 0; m < 4; ++m)
                *(f32x4*)(sWf + (16 * m + lr) * 12) = acc[m];
        } else if (lg == 1) {
#pragma unroll
            for (int m = 0; m < 4; ++m)
                sWf[(16 * m + lr) * 12 + 4] = acc[m][0];
        }
    }
    sync_lds();                                           // S6

    // ---- softmax over 5 gate logits ----
    if (tid < 64) {
        float g[5];
#pragma unroll
        for (int e = 0; e < 5; ++e) g[e] = sWf[tid * 12 + e];
        float mx = fmaxf(fmaxf(fmaxf(g[0], g[1]), fmaxf(g[2], g[3])), g[4]);
        float s = 0.f;
#pragma unroll
        for (int e = 0; e < 5; ++e) { g[e] = __expf(g[e] - mx); s += g[e]; }
        float inv = 1.f / s;
#pragma unroll
        for (int e = 0; e < 5; ++e) sWf[tid * 12 + e] = g[e] * inv;
    }

    // ---- G1: h = elu(hist @ vae_W1 + vae_b1), K=512; 2rh x 4cq, nt=4 ----
    // bf reads: 16ks x 2mm = 32/wave (redundancy 2); each bf feeds 4 MFMA.
    f32x4 acc1[2][4];
#pragma unroll
    for (int nt = 0; nt < 4; ++nt) {
        f32x4 bi = *(const f32x4*)(vb1 + 64 * cq + 16 * nt + 4 * lg);
        acc1[0][nt] = bi; acc1[1][nt] = bi;
    }
    __builtin_amdgcn_s_setprio(1);
#pragma unroll
    for (int ks = 0; ks < 16; ++ks) {
        f16x8 wf[4];
#pragma unroll
        for (int nt = 0; nt < 4; ++nt)
            wf[nt] = *(const f16x8*)(W1T + (64 * cq + 16 * nt + lr) * 512 + 32 * ks + 8 * lg);
#pragma unroll
        for (int mm = 0; mm < 2; ++mm) {
            int m = 2 * rh + mm;
            f16x8 bf = *(const f16x8*)(sS2 + (16 * m + lr) * 488 + 32 * ks + 8 * lg);
#pragma unroll
            for (int nt = 0; nt < 4; ++nt)
                acc1[mm][nt] = MFMA16(wf[nt], bf, acc1[mm][nt]);
        }
    }
    __builtin_amdgcn_s_setprio(0);
    // prefetch o_t (99 cols of S2) into regs before S2 is overwritten
    const int r_ot = tid >> 3, sub = tid & 7;
    ushort_t otv[13];
#pragma unroll
    for (int i = 0; i < 13; ++i) {
        int j = sub + 8 * i;
        if (j < 99) {
            int s;
            if (j < 3) s = j;
            else if (j < 12) { int jj = j - 3; int t = jj / 3;
                               s = 15 * (t + 1) + (jj - 3 * t); }
            else { int jj = j - 12; int t2 = jj / 29;
                   s = 164 + 145 * t2 + (jj - 29 * t2); }
            otv[i] = __builtin_bit_cast(ushort_t, sS2[r_ot * 488 + s]);
        }
    }
    float we5[5];
    sync_lds();                                           // S7: S2 reads done

    // write h (elu): rows 16(2rh+mm)+lr, cols 64cq+16nt+4lg
#pragma unroll
    for (int mm = 0; mm < 2; ++mm)
#pragma unroll
        for (int nt = 0; nt < 4; ++nt)
            elu_store4(sH + (16 * (2 * rh + mm) + lr) * 264 + 64 * cq + 16 * nt + 4 * lg, acc1[mm][nt]);
    // assemble buf0: o_t, zeros, z_E copy
#pragma unroll
    for (int i = 0; i < 13; ++i) {
        int j = sub + 8 * i;
        if (j < 99) sB0[r_ot * 200 + 5 + j] = __builtin_bit_cast(f16, otv[i]);
    }
    {
        char* b0r = (char*)sB0 + r_ot * 400;
        if (sub == 0) { *(uint2*)(b0r + 0) = (uint2){0u, 0u}; *(ushort_t*)(b0r + 8) = 0; }
        else if (sub == 1) { *(uint2*)(b0r + 280) = (uint2){0u, 0u}; }
        else if (sub == 2) { *(uint4*)(b0r + 352) = (uint4){0u,0u,0u,0u}; }
        else if (sub == 3) { *(uint4*)(b0r + 368) = (uint4){0u,0u,0u,0u}; }
    }
    {   // z_E -> buf0 cols 144..175 (512 quads, 1 per thread)
        int r = tid >> 3, c4 = tid & 7;
        uint2 v = *(uint2*)((char*)sZE + r * 80 + 8 * c4);
        *(uint2*)((char*)sB0 + r * 400 + 288 + 8 * c4) = v;
    }
#pragma unroll
    for (int e = 0; e < 5; ++e) we5[e] = sWf[(16 * em + lr) * 12 + e];
    sync_lds();                                           // S8

    // ---- G2: [v_pred|z_H] = h @ Wzv + bzv, K=256; waves 0..5 -> buf0 ----
    if (wv < 6) {
        int c = wv >> 1, h = wv & 1;
        f32x4 bz = *(const f32x4*)(BZV + 16 * c + 4 * lg);
        f32x4 acc[2]; acc[0] = bz; acc[1] = bz;
#pragma unroll
        for (int ks = 0; ks < 8; ++ks) {
            f16x8 wf = *(const f16x8*)(WZV + (16 * c + lr) * 256 + 32 * ks + 8 * lg);
#pragma unroll
            for (int mm = 0; mm < 2; ++mm) {
                int m = 2 * h + mm;
                f16x8 bf = *(const f16x8*)(sH + (16 * m + lr) * 264 + 32 * ks + 8 * lg);
                acc[mm] = MFMA16(wf, bf, acc[mm]);
            }
        }
        if (c < 2 || lg == 0) {
            int col = (c < 2) ? (108 + 16 * c + 4 * lg) : 104;
#pragma unroll
            for (int mm = 0; mm < 2; ++mm)
                store4(sB0 + (16 * (2 * h + mm) + lr) * 200 + col, acc[mm]);
        }
    }
    sync_lds();                                           // S9

    // ---- experts: 5 x (L1 K=192, L2 K=128, L3 K=128) ----
    // wave = (em = single m-tile) x (ecg = 64-col half); 1 bf read -> 4 MFMA.
    f32x4 oacc = (f32x4)0.f;

    for (int e = 0; e < 5; ++e) {       // runtime loop (R9 unroll = I$ thrash)
        // L1: h1 = elu(inp @ eW1 + eb1)
        {
            f32x4 acc[4];
#pragma unroll
            for (int nt = 0; nt < 4; ++nt)
                acc[nt] = *(const f32x4*)(eb1 + e * 128 + 64 * ecg + 16 * nt + 4 * lg);
            __builtin_amdgcn_s_setprio(1);
#pragma unroll
            for (int ks = 0; ks < 6; ++ks) {
                f16x8 bf = *(const f16x8*)(sB0 + (16 * em + lr) * 200 + 32 * ks + 8 * lg);
#pragma unroll
                for (int nt = 0; nt < 4; ++nt) {
                    f16x8 wf = *(const f16x8*)(E1T + (e * 128 + 64 * ecg + 16 * nt + lr) * 192 + 32 * ks + 8 * lg);
                    acc[nt] = MFMA16(wf, bf, acc[nt]);
                }
            }
            __builtin_amdgcn_s_setprio(0);
#pragma unroll
            for (int nt = 0; nt < 4; ++nt)
                elu_store4(sH1 + (16 * em + lr) * 136 + 64 * ecg + 16 * nt + 4 * lg, acc[nt]);
        }
        sync_lds();
        // L2: h2 = elu(h1 @ eW2 + eb2)
        {
            f32x4 acc[4];
#pragma unroll
            for (int nt = 0; nt < 4; ++nt)
                acc[nt] = *(const f32x4*)(eb2 + e * 128 + 64 * ecg + 16 * nt + 4 * lg);
            __builtin_amdgcn_s_setprio(1);
#pragma unroll
            for (int ks = 0; ks < 4; ++ks) {
                f16x8 bf = *(const f16x8*)(sH1 + (16 * em + lr) * 136 + 32 * ks + 8 * lg);
#pragma unroll
                for (int nt = 0; nt < 4; ++nt) {
                    f16x8 wf = *(const f16x8*)(E2T + (e * 128 + 64 * ecg + 16 * nt + lr) * 128 + 32 * ks + 8 * lg);
                    acc[nt] = MFMA16(wf, bf, acc[nt]);
                }
            }
            __builtin_amdgcn_s_setprio(0);
#pragma unroll
            for (int nt = 0; nt < 4; ++nt)
                elu_store4(sH2 + (16 * em + lr) * 136 + 64 * ecg + 16 * nt + 4 * lg, acc[nt]);
        }
        sync_lds();
        // L3: acts = h2 @ eW3 + eb3; rows 16*em, col-tile 16*ecg; weighted accumulate
        {
            f32x4 a3 = *(const f32x4*)(EB3P + e * 32 + 16 * ecg + 4 * lg);
#pragma unroll
            for (int ks = 0; ks < 4; ++ks) {
                f16x8 bf = *(const f16x8*)(sH2 + (16 * em + lr) * 136 + 32 * ks + 8 * lg);
                f16x8 wf = *(const f16x8*)(E3T + (e * 32 + 16 * ecg + lr) * 128 + 32 * ks + 8 * lg);
                a3 = MFMA16(wf, bf, a3);
            }
            float we = we5[e];
#pragma unroll
            for (int r = 0; r < 4; ++r) oacc[r] += we * a3[r];
        }
        sync_lds();
    }

    // ---- store out [64 x 29] fp32: row 16*em+lr, cols 16*ecg+4lg+r ----
    {
        int row = row0 + 16 * em + lr;
#pragma unroll
        for (int r = 0; r < 4; ++r) {
            int col = 16 * ecg + 4 * lg + r;
            if (col < 29) out[(size_t)row * 29 + col] = oacc[r];
        }
    }
}

extern "C" void kernel_launch(void* const* d_in, const int* in_sizes, int n_in,
                              void* d_out, int out_size, void* d_ws, size_t ws_size,
                              hipStream_t stream)
{
    (void)n_in; (void)out_size; (void)ws_size;
    const float* x   = (const float*)d_in[0];
    const float* vW1 = (const float*)d_in[1];
    const float* vb1 = (const float*)d_in[2];
    const float* vWz = (const float*)d_in[3];
    const float* vbz = (const float*)d_in[4];
    const float* vWv = (const float*)d_in[5];
    const float* vbv = (const float*)d_in[6];
    const float* aW1 = (const float*)d_in[7];
    const float* ab1 = (const float*)d_in[8];
    const float* aW2 = (const float*)d_in[9];
    const float* ab2 = (const float*)d_in[10];
    const float* gW1 = (const float*)d_in[11];
    const float* gb1 = (const float*)d_in[12];
    const float* gW2 = (const float*)d_in[13];
    const float* gb2 = (const float*)d_in[14];
    const float* eW1 = (const float*)d_in[15];
    const float* eb1 = (const float*)d_in[16];
    const float* eW2 = (const float*)d_in[17];
    const float* eb2 = (const float*)d_in[18];
    const float* eW3 = (const float*)d_in[19];
    const float* eb3 = (const float*)d_in[20];

    int n = in_sizes[0] / 975;

    prep_kernel<<<(380128 + 255) / 256, 256, 0, stream>>>(
        vW1, vWz, vWv, aW1, aW2, gW1, gW2, eW1, eW2, eW3, vbz, vbv, eb3, gb2, (char*)d_ws);

    moe_fused<<<n / 64, 512, 0, stream>>>(
        x, vb1, ab1, ab2, gb1, eb1, eb2, (const char*)d_ws, (float*)d_out);
}

// Round 12
// 314.790 us; speedup vs baseline: 1.9395x; 1.9395x over previous
//
#include <hip/hip_runtime.h>
#include <math.h>

typedef _Float16 f16;
typedef f16  f16x8 __attribute__((ext_vector_type(8)));
typedef float f32x4 __attribute__((ext_vector_type(4)));
typedef unsigned short ushort_t;

#define MFMA16(a, b, c) __builtin_amdgcn_mfma_f32_16x16x32_f16((a), (b), (c), 0, 0, 0)

// ---------------- workspace layout ----------------
// f16 element offsets (weights, repacked by prep):
#define W1T_E 0        // [256][512]  vae_W1^T, K permuted to S2 order
#define WZV_E 131072   // [48][256]   [vae_Wz | vae_Wv | 0]^T
#define A1T_E 143360   // [64][96]    ae_W1^T
#define A2T_E 149504   // [32][64]    ae_W2^T
#define G1T_E 151552   // [64][32]    gate_W1^T
#define G2T_E 153600   // [16][64]    gate_W2^T (cols 5..15 zero)
#define E1T_E 154624   // [5][128][192] eW1^T, K remapped to padded-192 inp layout
#define E2T_E 277504   // [5][128][128] eW2^T
#define E3T_E 359424   // [5][32][128]  eW3^T, cols 29..31 zero
#define F32_B 759808   // byte offset f32 appendix: BZV[48] | EB3P[160] | GB2P[16]
// inter-kernel buffers (byte offsets):
#define INP_B 1048576  // [N][200] f16 expert input (52.4 MB)
#define W5_B  53477376 // [N][8]   f32 gate weights (4.2 MB)

// ---------------- kernel A LDS (bytes), 64-row tile, 2 blocks/CU ----------------
#define S2_OFF   0       // [64][488] f16; alias: H[64][264]@0 + B0[64][200]@36864
#define B0_OFF   36864
#define ELEV_OFF 62528   // [64][104] f16 (pad 62464..62528); alias HA [64][72]
#define HA_OFF   62528
#define ZE_OFF   71744   // [64][32] f16
#define WF_OFF   75840   // [64][8] f32
#define SMEM_SZ  77888   // 2 x 77888 <= 163840 -> 2 blocks/CU

// ---------------- kernel B LDS (bytes), 128-row tile, 1 block/CU ----------------
#define IL_OFF   0       // [128][200] f16 = 51200
#define BH1_OFF  51200   // [128][136] f16 = 34816
#define BH2_OFF  86016   // [128][136] f16 = 34816
#define BW5_OFF  120832  // [128][8]  f32 = 4096
#define BSMEM    124928

__device__ __forceinline__ float elu_f(float v) {
    float e = __expf(v) - 1.f;
    return v > 0.f ? v : e;
}

// round-to-nearest f32x2 -> packed f16x2 (RTZ pkrtz biased the chain; keep RTN)
__device__ __forceinline__ unsigned pk(float a, float b) {
    ushort_t u0 = __builtin_bit_cast(ushort_t, (f16)a);
    ushort_t u1 = __builtin_bit_cast(ushort_t, (f16)b);
    return (unsigned)u0 | ((unsigned)u1 << 16);
}

__device__ __forceinline__ void store4(f16* p, f32x4 v) {
    uint2 t; t.x = pk(v[0], v[1]); t.y = pk(v[2], v[3]);
    *(uint2*)p = t;
}

__device__ __forceinline__ void elu_store4(f16* p, f32x4 v) {
    uint2 t; t.x = pk(elu_f(v[0]), elu_f(v[1])); t.y = pk(elu_f(v[2]), elu_f(v[3]));
    *(uint2*)p = t;
}

// LDS-only barrier: drains DS ops, leaves global loads in flight.
__device__ __forceinline__ void sync_lds() {
    asm volatile("s_waitcnt lgkmcnt(0)" ::: "memory");
    __builtin_amdgcn_s_barrier();
    asm volatile("" ::: "memory");
    __builtin_amdgcn_sched_barrier(0);
}

// ---------------- weight repack: fp32 -> f16, transposed/padded/permuted ----------------
__global__ void prep_kernel(const float* __restrict__ vW1, const float* __restrict__ vWz,
                            const float* __restrict__ vWv, const float* __restrict__ aW1,
                            const float* __restrict__ aW2, const float* __restrict__ gW1,
                            const float* __restrict__ gW2, const float* __restrict__ eW1,
                            const float* __restrict__ eW2, const float* __restrict__ eW3,
                            const float* __restrict__ vbz, const float* __restrict__ vbv,
                            const float* __restrict__ eb3, const float* __restrict__ gb2,
                            char* __restrict__ ws)
{
    int i = blockIdx.x * 256 + threadIdx.x;
    f16* H = (f16*)ws;
    if (i < 131072) {                                   // W1T [c=256][ks=512], S2-order K
        int c = i >> 9, ks = i & 511;
        int xcol = 12 + ks;
        float v = 0.f;
        if (xcol >= 15 && xcol <= 494) {
            int hc;
            if (xcol < 60) {
                int t = xcol / 15; int rm = xcol - 15 * t; int f = rm / 3;
                hc = 96 * f + 3 * (t - 1) + (rm - 3 * f);
            } else {
                int t2 = (xcol - 60) / 145; int rm = xcol - 60 - 145 * t2; int f = rm / 29;
                hc = 96 * f + 9 + 29 * t2 + (rm - 29 * f);
            }
            v = vW1[hc * 256 + c];
        }
        H[i] = (f16)v;
    } else if (i < 143360) {                            // WZV [c=48][k=256]
        int j = i - 131072; int c = j / 256, k = j - c * 256;
        float v = (c < 32) ? vWz[k * 32 + c] : ((c < 35) ? vWv[k * 3 + (c - 32)] : 0.f);
        H[i] = (f16)v;
    } else if (i < 149504) {                            // A1T [c=64][k=96]
        int j = i - 143360; int c = j / 96, k = j - c * 96;
        H[i] = (f16)aW1[k * 64 + c];
    } else if (i < 151552) {                            // A2T [c=32][k=64]
        int j = i - 149504; int c = j / 64, k = j - c * 64;
        H[i] = (f16)aW2[k * 32 + c];
    } else if (i < 153600) {                            // G1T [c=64][k=32]
        int j = i - 151552; int c = j / 32, k = j - c * 32;
        H[i] = (f16)gW1[k * 64 + c];
    } else if (i < 154624) {                            // G2T [c=16][k=64]
        int j = i - 153600; int c = j / 64, k = j - c * 64;
        H[i] = (f16)((c < 5) ? gW2[k * 5 + c] : 0.f);
    } else if (i < 277504) {                            // E1T [e][c=128][k=192] remapped
        int j = i - 154624; int e = j / 24576, jj = j - e * 24576;
        int c = jj / 192, k = jj - c * 192;
        int ko = (k >= 5 && k < 107)   ? (k - 5)
               : (k >= 108 && k < 140) ? (k - 6)
               : (k >= 144 && k < 176) ? (k - 10) : -1;
        H[i] = (f16)((ko >= 0) ? eW1[(e * 166 + ko) * 128 + c] : 0.f);
    } else if (i < 359424) {                            // E2T [e][c=128][k=128]
        int j = i - 277504; int e = j / 16384, jj = j - e * 16384;
        int c = jj / 128, k = jj - c * 128;
        H[i] = (f16)eW2[(e * 128 + k) * 128 + c];
    } else if (i < 379904) {                            // E3T [e][c=32][k=128]
        int j = i - 359424; int e = j / 4096, jj = j - e * 4096;
        int c = jj / 128, k = jj - c * 128;
        H[i] = (f16)((c < 29) ? eW3[(e * 128 + k) * 29 + c] : 0.f);
    } else if (i < 380128) {                            // f32 appendix
        int j = i - 379904;
        float* F = (float*)(ws + F32_B);
        float v;
        if (j < 48)       v = (j < 32) ? vbz[j] : ((j < 35) ? vbv[j - 32] : 0.f);
        else if (j < 208) { int t = j - 48; int e = t >> 5, c = t & 31;
                            v = (c < 29) ? eb3[e * 29 + c] : 0.f; }
        else              { int t = j - 208; v = (t < 5) ? gb2[t] : 0.f; }
        F[j] = v;
    }
}

// ---------------- kernel A: features (VAE+AE+gate), 64 rows/block, 512 thr ----------------
__global__ __launch_bounds__(512, 2) void moe_front(
    const float* __restrict__ x,
    const float* __restrict__ vb1,
    const float* __restrict__ ab1,
    const float* __restrict__ ab2,
    const float* __restrict__ gb1,
    char* __restrict__ ws)
{
    __shared__ __align__(16) char smem[SMEM_SZ];
    const int tid  = threadIdx.x;
    const int wv   = tid >> 6;      // 0..7
    const int lane = tid & 63;
    const int lr   = lane & 15;
    const int lg   = lane >> 4;
    const int rh   = wv & 1;        // row half
    const int cq   = wv >> 1;       // col quarter
    const int row0 = (int)blockIdx.x * 64;

    const f16* W1T = (const f16*)ws + W1T_E;
    const f16* WZV = (const f16*)ws + WZV_E;
    const f16* A1T = (const f16*)ws + A1T_E;
    const f16* A2T = (const f16*)ws + A2T_E;
    const f16* G1T = (const f16*)ws + G1T_E;
    const f16* G2T = (const f16*)ws + G2T_E;
    const float* BZV  = (const float*)(ws + F32_B);
    const float* GB2P = BZV + 208;

    f16* sS2 = (f16*)(smem + S2_OFF);     // stride 488
    f16* sEl = (f16*)(smem + ELEV_OFF);   // stride 104
    f16* sHA = (f16*)(smem + HA_OFF);     // stride 72
    f16* sZE = (f16*)(smem + ZE_OFF);     // stride 32
    f16* sH  = (f16*)(smem + S2_OFF);     // stride 264 (after G1)
    f16* sB0 = (f16*)(smem + B0_OFF);     // stride 200
    float* sWf = (float*)(smem + WF_OFF); // stride 8 f32

    // ---- P0: coalesced staging of S2 + elev (8 rows per wave) ----
    {
        if (tid < 16) *(unsigned*)(smem + 62464 + 4 * tid) = 0u;  // S2 tail pad
        const int sr0 = wv * 8;
        for (int rr = 0; rr < 8; ++rr) {
            const int r = sr0 + rr;
            const float* xr = x + (size_t)(row0 + r) * 975;
            if (lane < 48) {
                float a = xr[879 + 2 * lane], b = xr[880 + 2 * lane];
                *(unsigned*)(sEl + r * 104 + 2 * lane) = pk(a, b);
            }
            f16* dst = sS2 + r * 488;
#pragma unroll
            for (int j = 0; j < 4; ++j) {
                int p = j * 64 + lane;
                if (p < 244) {
                    float a = 0.f, b = 0.f;
                    if (p < 242) { a = xr[12 + 2 * p]; b = xr[13 + 2 * p]; }
                    *(unsigned*)(dst + 2 * p) = pk(a, b);
                }
            }
        }
    }
    sync_lds();                                           // S1

    // ---- G3: ha = elu(e_t @ ae_W1 + ae_b1); 2 row-halves x 4 col-quarters ----
    f32x4 g3acc[2];
    {
        f32x4 bi = *(const f32x4*)(ab1 + 16 * cq + 4 * lg);
        g3acc[0] = bi; g3acc[1] = bi;
#pragma unroll
        for (int ks = 0; ks < 3; ++ks) {
            f16x8 wf = *(const f16x8*)(A1T + (16 * cq + lr) * 96 + 32 * ks + 8 * lg);
#pragma unroll
            for (int mm = 0; mm < 2; ++mm) {
                int m = 2 * rh + mm;
                f16x8 bf = *(const f16x8*)(sEl + (16 * m + lr) * 104 + 32 * ks + 8 * lg);
                g3acc[mm] = MFMA16(wf, bf, g3acc[mm]);
            }
        }
    }
    sync_lds();                                           // S2: elev reads done
#pragma unroll
    for (int mm = 0; mm < 2; ++mm)
        elu_store4(sHA + (16 * (2 * rh + mm) + lr) * 72 + 16 * cq + 4 * lg, g3acc[mm]);
    sync_lds();                                           // S3

    // ---- G4 (waves 0..3): z_E = ha @ ae_W2 + ae_b2 -> sZE ----
    if (wv < 4) {
        int c = wv >> 1, h = wv & 1;
        f32x4 bi = *(const f32x4*)(ab2 + 16 * c + 4 * lg);
        f32x4 acc[2]; acc[0] = bi; acc[1] = bi;
#pragma unroll
        for (int ks = 0; ks < 2; ++ks) {
            f16x8 wf = *(const f16x8*)(A2T + (16 * c + lr) * 64 + 32 * ks + 8 * lg);
#pragma unroll
            for (int mm = 0; mm < 2; ++mm) {
                int m = 2 * h + mm;
                f16x8 bf = *(const f16x8*)(sHA + (16 * m + lr) * 72 + 32 * ks + 8 * lg);
                acc[mm] = MFMA16(wf, bf, acc[mm]);
            }
        }
#pragma unroll
        for (int mm = 0; mm < 2; ++mm)
            store4(sZE + (16 * (2 * h + mm) + lr) * 32 + 16 * c + 4 * lg, acc[mm]);
    }
    sync_lds();                                           // S4

    // ---- gate hidden: gh = elu(z_E @ gate_W1 + gate_b1), K=32 -> sHA ----
    {
        f32x4 bi = *(const f32x4*)(gb1 + 16 * cq + 4 * lg);
        f32x4 acc[2]; acc[0] = bi; acc[1] = bi;
        f16x8 wf = *(const f16x8*)(G1T + (16 * cq + lr) * 32 + 8 * lg);
#pragma unroll
        for (int mm = 0; mm < 2; ++mm) {
            int m = 2 * rh + mm;
            f16x8 bf = *(const f16x8*)(sZE + (16 * m + lr) * 32 + 8 * lg);
            acc[mm] = MFMA16(wf, bf, acc[mm]);
        }
#pragma unroll
        for (int mm = 0; mm < 2; ++mm)
            elu_store4(sHA + (16 * (2 * rh + mm) + lr) * 72 + 16 * cq + 4 * lg, acc[mm]);
    }
    sync_lds();                                           // S5

    // ---- gate logits (wave 0) -> sWf; guarded (R2/R3 OOB lesson) ----
    if (wv == 0) {
        f32x4 bi = *(const f32x4*)(GB2P + 4 * lg);
        f32x4 acc[4];
#pragma unroll
        for (int m = 0; m < 4; ++m) acc[m] = bi;
#pragma unroll
        for (int ks = 0; ks < 2; ++ks) {
            f16x8 wf = *(const f16x8*)(G2T + lr * 64 + 32 * ks + 8 * lg);
#pragma unroll
            for (int m = 0; m < 4; ++m) {
                f16x8 bf = *(const f16x8*)(sHA + (16 * m + lr) * 72 + 32 * ks + 8 * lg);
                acc[m] = MFMA16(wf, bf, acc[m]);
            }
        }
        if (lg == 0) {
#pragma unroll
            for (int m = 0; m < 4; ++m)
                *(f32x4*)(sWf + (16 * m + lr) * 8) = acc[m];
        } else if (lg == 1) {
#pragma unroll
            for (int m = 0; m < 4; ++m)
                sWf[(16 * m + lr) * 8 + 4] = acc[m][0];
        }
    }
    sync_lds();                                           // S6

    // ---- softmax over 5 gate logits ----
    if (tid < 64) {
        float g[5];
#pragma unroll
        for (int e = 0; e < 5; ++e) g[e] = sWf[tid * 8 + e];
        float mx = fmaxf(fmaxf(fmaxf(g[0], g[1]), fmaxf(g[2], g[3])), g[4]);
        float s = 0.f;
#pragma unroll
        for (int e = 0; e < 5; ++e) { g[e] = __expf(g[e] - mx); s += g[e]; }
        float inv = 1.f / s;
#pragma unroll
        for (int e = 0; e < 5; ++e) sWf[tid * 8 + e] = g[e] * inv;
        sWf[tid * 8 + 5] = 0.f; sWf[tid * 8 + 6] = 0.f; sWf[tid * 8 + 7] = 0.f;
    }

    // ---- G1: h = elu(hist @ vae_W1 + vae_b1), K=512; 32 cols/wave (2 nt) ----
    f32x4 acc1[4][2];
#pragma unroll
    for (int nt = 0; nt < 2; ++nt) {
        f32x4 bi = *(const f32x4*)(vb1 + 32 * wv + 16 * nt + 4 * lg);
#pragma unroll
        for (int m = 0; m < 4; ++m) acc1[m][nt] = bi;
    }
    __builtin_amdgcn_s_setprio(1);
#pragma unroll
    for (int ks = 0; ks < 16; ++ks) {
        f16x8 wf[2];
#pragma unroll
        for (int nt = 0; nt < 2; ++nt)
            wf[nt] = *(const f16x8*)(W1T + (32 * wv + 16 * nt + lr) * 512 + 32 * ks + 8 * lg);
#pragma unroll
        for (int m = 0; m < 4; ++m) {
            f16x8 bf = *(const f16x8*)(sS2 + (16 * m + lr) * 488 + 32 * ks + 8 * lg);
#pragma unroll
            for (int nt = 0; nt < 2; ++nt)
                acc1[m][nt] = MFMA16(wf[nt], bf, acc1[m][nt]);
        }
    }
    __builtin_amdgcn_s_setprio(0);
    // prefetch o_t (99 cols of S2) into regs before S2 is overwritten
    const int r_ot = tid >> 3, sub = tid & 7;
    ushort_t otv[13];
#pragma unroll
    for (int i = 0; i < 13; ++i) {
        int j = sub + 8 * i;
        if (j < 99) {
            int s;
            if (j < 3) s = j;
            else if (j < 12) { int jj = j - 3; int t = jj / 3;
                               s = 15 * (t + 1) + (jj - 3 * t); }
            else { int jj = j - 12; int t2 = jj / 29;
                   s = 164 + 145 * t2 + (jj - 29 * t2); }
            otv[i] = __builtin_bit_cast(ushort_t, sS2[r_ot * 488 + s]);
        }
    }
    sync_lds();                                           // S7: S2 reads done

    // write h (elu); assemble B0
#pragma unroll
    for (int m = 0; m < 4; ++m)
#pragma unroll
        for (int nt = 0; nt < 2; ++nt)
            elu_store4(sH + (16 * m + lr) * 264 + 32 * wv + 16 * nt + 4 * lg, acc1[m][nt]);
#pragma unroll
    for (int i = 0; i < 13; ++i) {
        int j = sub + 8 * i;
        if (j < 99) sB0[r_ot * 200 + 5 + j] = __builtin_bit_cast(f16, otv[i]);
    }
    {
        char* b0r = (char*)sB0 + r_ot * 400;
        if (sub == 0) { *(uint2*)(b0r + 0) = (uint2){0u, 0u}; *(ushort_t*)(b0r + 8) = 0; }
        else if (sub == 1) { *(uint2*)(b0r + 280) = (uint2){0u, 0u}; }
        else if (sub == 2) { *(uint4*)(b0r + 352) = (uint4){0u,0u,0u,0u}; }
        else if (sub == 3) { *(uint4*)(b0r + 368) = (uint4){0u,0u,0u,0u}; }
    }
    {   // z_E -> B0 cols 144..175
        int r = tid >> 3, c4 = tid & 7;
        uint2 v = *(uint2*)((char*)sZE + r * 64 + 8 * c4);
        *(uint2*)((char*)sB0 + r * 400 + 288 + 8 * c4) = v;
    }
    sync_lds();                                           // S8

    // ---- G2: [v_pred|z_H] = h @ Wzv + bzv, K=256; waves 0..5 -> B0 ----
    if (wv < 6) {
        int c = wv >> 1, h = wv & 1;
        f32x4 bz = *(const f32x4*)(BZV + 16 * c + 4 * lg);
        f32x4 acc[2]; acc[0] = bz; acc[1] = bz;
#pragma unroll
        for (int ks = 0; ks < 8; ++ks) {
            f16x8 wf = *(const f16x8*)(WZV + (16 * c + lr) * 256 + 32 * ks + 8 * lg);
#pragma unroll
            for (int mm = 0; mm < 2; ++mm) {
                int m = 2 * h + mm;
                f16x8 bf = *(const f16x8*)(sH + (16 * m + lr) * 264 + 32 * ks + 8 * lg);
                acc[mm] = MFMA16(wf, bf, acc[mm]);
            }
        }
        if (c < 2 || lg == 0) {
            int col = (c < 2) ? (108 + 16 * c + 4 * lg) : 104;
#pragma unroll
            for (int mm = 0; mm < 2; ++mm)
                store4(sB0 + (16 * (2 * h + mm) + lr) * 200 + col, acc[mm]);
        }
    }
    sync_lds();                                           // S9: B0 + WF final

    // ---- copy-out: B0 [64][200] f16 + WF [64][8] f32 -> workspace ----
    {
        const uint4* srcB = (const uint4*)sB0;
        uint4* dstB = (uint4*)(ws + INP_B + (size_t)row0 * 400);
#pragma unroll
        for (int it = 0; it < 4; ++it) {
            int idx = it * 512 + tid;
            if (idx < 1600) dstB[idx] = srcB[idx];
        }
        const uint4* srcW = (const uint4*)sWf;
        uint4* dstW = (uint4*)(ws + W5_B + (size_t)row0 * 32);
        if (tid < 128) dstW[tid] = srcW[tid];
    }
}

// ---------------- kernel B: experts, 128 rows/block, 512 thr ----------------
__global__ __launch_bounds__(512, 2) void moe_experts(
    const char* __restrict__ ws,
    const float* __restrict__ eb1,
    const float* __restrict__ eb2,
    float* __restrict__ out)
{
    __shared__ __align__(16) char smem[BSMEM];
    const int tid  = threadIdx.x;
    const int wv   = tid >> 6;      // 0..7
    const int lane = tid & 63;
    const int lr   = lane & 15;
    const int lg   = lane >> 4;
    const int row0 = (int)blockIdx.x * 128;

    const f16* E1T = (const f16*)ws + E1T_E;
    const f16* E2T = (const f16*)ws + E2T_E;
    const f16* E3T = (const f16*)ws + E3T_E;
    const float* EB3P = (const float*)(ws + F32_B) + 48;

    f16* IL = (f16*)(smem + IL_OFF);      // stride 200
    f16* H1 = (f16*)(smem + BH1_OFF);     // stride 136
    f16* H2 = (f16*)(smem + BH2_OFF);     // stride 136
    float* W5 = (float*)(smem + BW5_OFF); // stride 8

    // ---- stage inp tile (pure linear, coalesced) + w5 tile ----
    {
        const uint4* srcB = (const uint4*)(ws + INP_B + (size_t)row0 * 400);
#pragma unroll
        for (int it = 0; it < 7; ++it) {
            int idx = it * 512 + tid;
            if (idx < 3200) ((uint4*)IL)[idx] = srcB[idx];
        }
        const uint4* srcW = (const uint4*)(ws + W5_B + (size_t)row0 * 32);
        if (tid < 256) ((uint4*)W5)[tid] = srcW[tid];
    }
    __syncthreads();

    float we5[5];
#pragma unroll
    for (int e = 0; e < 5; ++e) we5[e] = W5[(16 * wv + lr) * 8 + e];

    f32x4 oacc[2]; oacc[0] = (f32x4)0.f; oacc[1] = (f32x4)0.f;

    for (int e = 0; e < 5; ++e) {
        // L1: h1 = elu(inp @ eW1 + eb1); wave = 16-col tile, 8 m-tiles each
        {
            f32x4 bi = *(const f32x4*)(eb1 + e * 128 + 16 * wv + 4 * lg);
            f32x4 acc[8];
#pragma unroll
            for (int m = 0; m < 8; ++m) acc[m] = bi;
            __builtin_amdgcn_s_setprio(1);
#pragma unroll
            for (int ks = 0; ks < 6; ++ks) {
                f16x8 wf = *(const f16x8*)(E1T + (e * 128 + 16 * wv + lr) * 192 + 32 * ks + 8 * lg);
#pragma unroll
                for (int m = 0; m < 8; ++m) {
                    f16x8 bf = *(const f16x8*)(IL + (16 * m + lr) * 200 + 32 * ks + 8 * lg);
                    acc[m] = MFMA16(wf, bf, acc[m]);
                }
            }
            __builtin_amdgcn_s_setprio(0);
#pragma unroll
            for (int m = 0; m < 8; ++m)
                elu_store4(H1 + (16 * m + lr) * 136 + 16 * wv + 4 * lg, acc[m]);
        }
        __syncthreads();
        // L2: h2 = elu(h1 @ eW2 + eb2)
        {
            f32x4 bi = *(const f32x4*)(eb2 + e * 128 + 16 * wv + 4 * lg);
            f32x4 acc[8];
#pragma unroll
            for (int m = 0; m < 8; ++m) acc[m] = bi;
            __builtin_amdgcn_s_setprio(1);
#pragma unroll
            for (int ks = 0; ks < 4; ++ks) {
                f16x8 wf = *(const f16x8*)(E2T + (e * 128 + 16 * wv + lr) * 128 + 32 * ks + 8 * lg);
#pragma unroll
                for (int m = 0; m < 8; ++m) {
                    f16x8 bf = *(const f16x8*)(H1 + (16 * m + lr) * 136 + 32 * ks + 8 * lg);
                    acc[m] = MFMA16(wf, bf, acc[m]);
                }
            }
            __builtin_amdgcn_s_setprio(0);
#pragma unroll
            for (int m = 0; m < 8; ++m)
                elu_store4(H2 + (16 * m + lr) * 136 + 16 * wv + 4 * lg, acc[m]);
        }
        __syncthreads();
        // L3: acts = h2 @ eW3 + eb3; wave = m-tile wv, both 16-col tiles; weighted acc.
        // No barrier after: L3 reads H2 only; next L1 writes H1 (disjoint); the
        // post-L1 barrier separates these H2 reads from next L2's H2 writes.
        {
            f32x4 a3[2];
#pragma unroll
            for (int ct = 0; ct < 2; ++ct)
                a3[ct] = *(const f32x4*)(EB3P + e * 32 + 16 * ct + 4 * lg);
#pragma unroll
            for (int ks = 0; ks < 4; ++ks) {
                f16x8 bf = *(const f16x8*)(H2 + (16 * wv + lr) * 136 + 32 * ks + 8 * lg);
#pragma unroll
                for (int ct = 0; ct < 2; ++ct) {
                    f16x8 wf = *(const f16x8*)(E3T + (e * 32 + 16 * ct + lr) * 128 + 32 * ks + 8 * lg);
                    a3[ct] = MFMA16(wf, bf, a3[ct]);
                }
            }
            float we = we5[e];
#pragma unroll
            for (int ct = 0; ct < 2; ++ct)
#pragma unroll
                for (int r = 0; r < 4; ++r) oacc[ct][r] += we * a3[ct][r];
        }
    }

    // ---- store out: rows 16*wv+lr (+row0), cols 16*ct+4*lg+r ----
    {
        int row = row0 + 16 * wv + lr;
#pragma unroll
        for (int ct = 0; ct < 2; ++ct)
#pragma unroll
            for (int r = 0; r < 4; ++r) {
                int col = 16 * ct + 4 * lg + r;
                if (col < 29) out[(size_t)row * 29 + col] = oacc[ct][r];
            }
    }
}

extern "C" void kernel_launch(void* const* d_in, const int* in_sizes, int n_in,
                              void* d_out, int out_size, void* d_ws, size_t ws_size,
                              hipStream_t stream)
{
    (void)n_in; (void)out_size; (void)ws_size;
    const float* x   = (const float*)d_in[0];
    const float* vW1 = (const float*)d_in[1];
    const float* vb1 = (const float*)d_in[2];
    const float* vWz = (const float*)d_in[3];
    const float* vbz = (const float*)d_in[4];
    const float* vWv = (const float*)d_in[5];
    const float* vbv = (const float*)d_in[6];
    const float* aW1 = (const float*)d_in[7];
    const float* ab1 = (const float*)d_in[8];
    const float* aW2 = (const float*)d_in[9];
    const float* ab2 = (const float*)d_in[10];
    const float* gW1 = (const float*)d_in[11];
    const float* gb1 = (const float*)d_in[12];
    const float* gW2 = (const float*)d_in[13];
    const float* gb2 = (const float*)d_in[14];
    const float* eW1 = (const float*)d_in[15];
    const float* eb1 = (const float*)d_in[16];
    const float* eW2 = (const float*)d_in[17];
    const float* eb2 = (const float*)d_in[18];
    const float* eW3 = (const float*)d_in[19];
    const float* eb3 = (const float*)d_in[20];

    int n = in_sizes[0] / 975;

    prep_kernel<<<(380128 + 255) / 256, 256, 0, stream>>>(
        vW1, vWz, vWv, aW1, aW2, gW1, gW2, eW1, eW2, eW3, vbz, vbv, eb3, gb2, (char*)d_ws);

    moe_front<<<n / 64, 512, 0, stream>>>(
        x, vb1, ab1, ab2, gb1, (char*)d_ws);

    moe_experts<<<n / 128, 512, 0, stream>>>(
        (const char*)d_ws, eb1, eb2, (float*)d_out);
}

// Round 13
// 284.250 us; speedup vs baseline: 2.1479x; 1.1074x over previous
//
#include <hip/hip_runtime.h>
#include <math.h>

typedef _Float16 f16;
typedef f16  f16x8 __attribute__((ext_vector_type(8)));
typedef float f32x4 __attribute__((ext_vector_type(4)));
typedef float f32x4u __attribute__((ext_vector_type(4), aligned(4)));  // x rows are 4B-aligned
typedef unsigned short ushort_t;

#define MFMA16(a, b, c) __builtin_amdgcn_mfma_f32_16x16x32_f16((a), (b), (c), 0, 0, 0)

// ---------------- workspace layout (f16 element offsets) ----------------
#define W1T_E 0        // [256][512]  vae_W1^T, K permuted to S2 order
#define WZV_E 131072   // [48][256]   [vae_Wz | vae_Wv | 0]^T
#define A1T_E 143360   // [64][96]    ae_W1^T
#define A2T_E 149504   // [32][64]    ae_W2^T
#define G1T_E 151552   // [64][32]    gate_W1^T
#define G2T_E 153600   // [16][64]    gate_W2^T (cols 5..15 zero)
#define E1T_E 154624   // [5][128][192] eW1^T, K remapped to padded-192 buf0 layout
#define E2T_E 277504   // [5][128][128] eW2^T
#define E3T_E 359424   // [5][32][128]  eW3^T, cols 29..31 zero
#define F32_B 759808   // f32 appendix: BZV[48] | EB3P[160] | GB2P[16]

// ---------------- LDS layout (bytes), 64-row tile, 2 blocks/CU ----------------
#define S2_OFF   0       // [64][488] f16; alias: H[64][264]@0 + B0[64][200]@36864
#define B0_OFF   36864
#define H2_OFF   17408   // experts: H1@0, H2 here
#define ELEV_OFF 62528   // [64][104] f16 (64B zero pad at 62464); alias HA [64][72]
#define HA_OFF   62528
#define ZE_OFF   71744   // [64][40] f16 (stride 40: ~2-way banks, was 8-way at 32)
#define WF_OFF   76864   // [64][12] f32 (stride 12: aligned + 2-way)
#define SMEM_SZ  79936   // 2 x 79936 <= 163840 -> 2 blocks/CU (512 thr: 16 waves/CU)

__device__ __forceinline__ float elu_f(float v) {
    float e = __expf(v) - 1.f;
    return v > 0.f ? v : e;
}

// round-to-nearest f32x2 -> packed f16x2 (RTZ pkrtz biased the chain; keep RTN)
__device__ __forceinline__ unsigned pk(float a, float b) {
    ushort_t u0 = __builtin_bit_cast(ushort_t, (f16)a);
    ushort_t u1 = __builtin_bit_cast(ushort_t, (f16)b);
    return (unsigned)u0 | ((unsigned)u1 << 16);
}

__device__ __forceinline__ void store4(f16* p, f32x4 v) {
    uint2 t; t.x = pk(v[0], v[1]); t.y = pk(v[2], v[3]);
    *(uint2*)p = t;
}

__device__ __forceinline__ void elu_store4(f16* p, f32x4 v) {
    uint2 t; t.x = pk(elu_f(v[0]), elu_f(v[1])); t.y = pk(elu_f(v[2]), elu_f(v[3]));
    *(uint2*)p = t;
}

// LDS-only barrier: drains DS ops but leaves global loads in flight.
__device__ __forceinline__ void sync_lds() {
    asm volatile("s_waitcnt lgkmcnt(0)" ::: "memory");
    __builtin_amdgcn_s_barrier();
    asm volatile("" ::: "memory");
    __builtin_amdgcn_sched_barrier(0);
}

// ---------------- weight repack: fp32 -> f16, transposed/padded/permuted ----------------
__global__ void prep_kernel(const float* __restrict__ vW1, const float* __restrict__ vWz,
                            const float* __restrict__ vWv, const float* __restrict__ aW1,
                            const float* __restrict__ aW2, const float* __restrict__ gW1,
                            const float* __restrict__ gW2, const float* __restrict__ eW1,
                            const float* __restrict__ eW2, const float* __restrict__ eW3,
                            const float* __restrict__ vbz, const float* __restrict__ vbv,
                            const float* __restrict__ eb3, const float* __restrict__ gb2,
                            char* __restrict__ ws)
{
    int i = blockIdx.x * 256 + threadIdx.x;
    f16* H = (f16*)ws;
    if (i < 131072) {                                   // W1T [c=256][ks=512], S2-order K
        int c = i >> 9, ks = i & 511;
        int xcol = 12 + ks;
        float v = 0.f;
        if (xcol >= 15 && xcol <= 494) {
            int hc;
            if (xcol < 60) {
                int t = xcol / 15; int rm = xcol - 15 * t; int f = rm / 3;
                hc = 96 * f + 3 * (t - 1) + (rm - 3 * f);
            } else {
                int t2 = (xcol - 60) / 145; int rm = xcol - 60 - 145 * t2; int f = rm / 29;
                hc = 96 * f + 9 + 29 * t2 + (rm - 29 * f);
            }
            v = vW1[hc * 256 + c];
        }
        H[i] = (f16)v;
    } else if (i < 143360) {                            // WZV [c=48][k=256]
        int j = i - 131072; int c = j / 256, k = j - c * 256;
        float v = (c < 32) ? vWz[k * 32 + c] : ((c < 35) ? vWv[k * 3 + (c - 32)] : 0.f);
        H[i] = (f16)v;
    } else if (i < 149504) {                            // A1T [c=64][k=96]
        int j = i - 143360; int c = j / 96, k = j - c * 96;
        H[i] = (f16)aW1[k * 64 + c];
    } else if (i < 151552) {                            // A2T [c=32][k=64]
        int j = i - 149504; int c = j / 64, k = j - c * 64;
        H[i] = (f16)aW2[k * 32 + c];
    } else if (i < 153600) {                            // G1T [c=64][k=32]
        int j = i - 151552; int c = j / 32, k = j - c * 32;
        H[i] = (f16)gW1[k * 64 + c];
    } else if (i < 154624) {                            // G2T [c=16][k=64]
        int j = i - 153600; int c = j / 64, k = j - c * 64;
        H[i] = (f16)((c < 5) ? gW2[k * 5 + c] : 0.f);
    } else if (i < 277504) {                            // E1T [e][c=128][k=192] remapped
        int j = i - 154624; int e = j / 24576, jj = j - e * 24576;
        int c = jj / 192, k = jj - c * 192;
        int ko = (k >= 5 && k < 107)   ? (k - 5)
               : (k >= 108 && k < 140) ? (k - 6)
               : (k >= 144 && k < 176) ? (k - 10) : -1;
        H[i] = (f16)((ko >= 0) ? eW1[(e * 166 + ko) * 128 + c] : 0.f);
    } else if (i < 359424) {                            // E2T [e][c=128][k=128]
        int j = i - 277504; int e = j / 16384, jj = j - e * 16384;
        int c = jj / 128, k = jj - c * 128;
        H[i] = (f16)eW2[(e * 128 + k) * 128 + c];
    } else if (i < 379904) {                            // E3T [e][c=32][k=128]
        int j = i - 359424; int e = j / 4096, jj = j - e * 4096;
        int c = jj / 128, k = jj - c * 128;
        H[i] = (f16)((c < 29) ? eW3[(e * 128 + k) * 29 + c] : 0.f);
    } else if (i < 380128) {                            // f32 appendix
        int j = i - 379904;
        float* F = (float*)(ws + F32_B);
        float v;
        if (j < 48)       v = (j < 32) ? vbz[j] : ((j < 35) ? vbv[j - 32] : 0.f);
        else if (j < 208) { int t = j - 48; int e = t >> 5, c = t & 31;
                            v = (c < 29) ? eb3[e * 29 + c] : 0.f; }
        else              { int t = j - 208; v = (t < 5) ? gb2[t] : 0.f; }
        F[j] = v;
    }
}

// ---------------- fused actor: 64 rows/block, 512 threads ----------------
__global__ __launch_bounds__(512, 4) void moe_fused(
    const float* __restrict__ x,
    const float* __restrict__ vb1,
    const float* __restrict__ ab1,
    const float* __restrict__ ab2,
    const float* __restrict__ gb1,
    const float* __restrict__ eb1,
    const float* __restrict__ eb2,
    const char* __restrict__ ws,
    float* __restrict__ out)
{
    __shared__ __align__(16) char smem[SMEM_SZ];
    const int tid  = threadIdx.x;
    const int wv   = tid >> 6;      // 0..7
    const int lane = tid & 63;
    const int lr   = lane & 15;
    const int lg   = lane >> 4;
    const int rh   = wv & 1;        // row half for G3 (2 m-tiles)
    const int cq   = wv >> 1;       // col quarter 0..3
    const int row0 = (int)blockIdx.x * 64;

    const f16* W1T = (const f16*)ws + W1T_E;
    const f16* WZV = (const f16*)ws + WZV_E;
    const f16* A1T = (const f16*)ws + A1T_E;
    const f16* A2T = (const f16*)ws + A2T_E;
    const f16* G1T = (const f16*)ws + G1T_E;
    const f16* G2T = (const f16*)ws + G2T_E;
    const f16* E1T = (const f16*)ws + E1T_E;
    const f16* E2T = (const f16*)ws + E2T_E;
    const f16* E3T = (const f16*)ws + E3T_E;
    const float* BZV  = (const float*)(ws + F32_B);
    const float* EB3P = BZV + 48;
    const float* GB2P = BZV + 208;

    f16* sS2 = (f16*)(smem + S2_OFF);     // stride 488
    f16* sEl = (f16*)(smem + ELEV_OFF);   // stride 104
    f16* sHA = (f16*)(smem + HA_OFF);     // stride 72
    f16* sZE = (f16*)(smem + ZE_OFF);     // stride 40
    f16* sH  = (f16*)(smem + S2_OFF);     // stride 264 (after G1)
    f16* sB0 = (f16*)(smem + B0_OFF);     // stride 200
    f16* sH1 = (f16*)(smem + S2_OFF);     // stride 136 (experts)
    f16* sH2 = (f16*)(smem + H2_OFF);     // stride 136
    float* sWf = (float*)(smem + WF_OFF); // stride 12 f32

    // ---- P0: wide staging. Per row: 61x16B S2 chunks (lanes<61), 12x16B elev
    // chunks (lanes<12). dwordx4 global loads (4B-aligned type) + b128 LDS writes.
    // S2 cols 483..487 get real-but-unused x values (zero weights) - finite, safe.
    {
        if (tid < 16) *(unsigned*)(smem + 62464 + 4 * tid) = 0u;  // S2 tail pad
        const int sr0 = wv * 8;
#pragma unroll 2
        for (int rr = 0; rr < 8; ++rr) {
            const int r = sr0 + rr;
            const float* xr = x + (size_t)(row0 + r) * 975;
            if (lane < 61) {
                f32x4u a = *(const f32x4u*)(xr + 12 + 8 * lane);
                f32x4u b = *(const f32x4u*)(xr + 16 + 8 * lane);
                uint4 t; t.x = pk(a[0], a[1]); t.y = pk(a[2], a[3]);
                t.z = pk(b[0], b[1]); t.w = pk(b[2], b[3]);
                *(uint4*)(sS2 + r * 488 + 8 * lane) = t;
            }
            if (lane < 12) {
                f32x4u a = *(const f32x4u*)(xr + 879 + 8 * lane);
                f32x4u b = *(const f32x4u*)(xr + 883 + 8 * lane);
                uint4 t; t.x = pk(a[0], a[1]); t.y = pk(a[2], a[3]);
                t.z = pk(b[0], b[1]); t.w = pk(b[2], b[3]);
                *(uint4*)(sEl + r * 104 + 8 * lane) = t;
            }
        }
    }
    sync_lds();                                           // S1

    // ---- G3: ha = elu(e_t @ ae_W1 + ae_b1); 2 row-halves x 4 col-quarters ----
    f32x4 g3acc[2];
    {
        f32x4 bi = *(const f32x4*)(ab1 + 16 * cq + 4 * lg);
        g3acc[0] = bi; g3acc[1] = bi;
#pragma unroll
        for (int ks = 0; ks < 3; ++ks) {
            f16x8 wf = *(const f16x8*)(A1T + (16 * cq + lr) * 96 + 32 * ks + 8 * lg);
#pragma unroll
            for (int mm = 0; mm < 2; ++mm) {
                int m = 2 * rh + mm;
                f16x8 bf = *(const f16x8*)(sEl + (16 * m + lr) * 104 + 32 * ks + 8 * lg);
                g3acc[mm] = MFMA16(wf, bf, g3acc[mm]);
            }
        }
    }
    sync_lds();                                           // S2: elev reads done
#pragma unroll
    for (int mm = 0; mm < 2; ++mm)
        elu_store4(sHA + (16 * (2 * rh + mm) + lr) * 72 + 16 * cq + 4 * lg, g3acc[mm]);
    sync_lds();                                           // S3

    // ---- G4 (waves 0..3): z_E = ha @ ae_W2 + ae_b2 -> sZE ----
    if (wv < 4) {
        int c = wv >> 1, h = wv & 1;
        f32x4 bi = *(const f32x4*)(ab2 + 16 * c + 4 * lg);
        f32x4 acc[2]; acc[0] = bi; acc[1] = bi;
#pragma unroll
        for (int ks = 0; ks < 2; ++ks) {
            f16x8 wf = *(const f16x8*)(A2T + (16 * c + lr) * 64 + 32 * ks + 8 * lg);
#pragma unroll
            for (int mm = 0; mm < 2; ++mm) {
                int m = 2 * h + mm;
                f16x8 bf = *(const f16x8*)(sHA + (16 * m + lr) * 72 + 32 * ks + 8 * lg);
                acc[mm] = MFMA16(wf, bf, acc[mm]);
            }
        }
#pragma unroll
        for (int mm = 0; mm < 2; ++mm)
            store4(sZE + (16 * (2 * h + mm) + lr) * 40 + 16 * c + 4 * lg, acc[mm]);
    }
    sync_lds();                                           // S4

    // ---- gate hidden: gh = elu(z_E @ gate_W1 + gate_b1), K=32 -> sHA ----
    {
        f32x4 bi = *(const f32x4*)(gb1 + 16 * cq + 4 * lg);
        f32x4 acc[2]; acc[0] = bi; acc[1] = bi;
        f16x8 wf = *(const f16x8*)(G1T + (16 * cq + lr) * 32 + 8 * lg);
#pragma unroll
        for (int mm = 0; mm < 2; ++mm) {
            int m = 2 * rh + mm;
            f16x8 bf = *(const f16x8*)(sZE + (16 * m + lr) * 40 + 8 * lg);
            acc[mm] = MFMA16(wf, bf, acc[mm]);
        }
#pragma unroll
        for (int mm = 0; mm < 2; ++mm)
            elu_store4(sHA + (16 * (2 * rh + mm) + lr) * 72 + 16 * cq + 4 * lg, acc[mm]);
    }
    sync_lds();                                           // S5

    // ---- gate logits (wave 0) -> sWf; guarded (R2/R3 OOB lesson) ----
    if (wv == 0) {
        f32x4 bi = *(const f32x4*)(GB2P + 4 * lg);
        f32x4 acc[4];
#pragma unroll
        for (int m = 0; m < 4; ++m) acc[m] = bi;
#pragma unroll
        for (int ks = 0; ks < 2; ++ks) {
            f16x8 wf = *(const f16x8*)(G2T + lr * 64 + 32 * ks + 8 * lg);
#pragma unroll
            for (int m = 0; m < 4; ++m) {
                f16x8 bf = *(const f16x8*)(sHA + (16 * m + lr) * 72 + 32 * ks + 8 * lg);
                acc[m] = MFMA16(wf, bf, acc[m]);
            }
        }
        if (lg == 0) {
#pragma unroll
            for (int m = 0; m < 4; ++m)
                *(f32x4*)(sWf + (16 * m + lr) * 12) = acc[m];
        } else if (lg == 1) {
#pragma unroll
            for (int m = 0; m < 4; ++m)
                sWf[(16 * m + lr) * 12 + 4] = acc[m][0];
        }
    }
    sync_lds();                                           // S6

    // ---- softmax over 5 gate logits ----
    if (tid < 64) {
        float g[5];
#pragma unroll
        for (int e = 0; e < 5; ++e) g[e] = sWf[tid * 12 + e];
        float mx = fmaxf(fmaxf(fmaxf(g[0], g[1]), fmaxf(g[2], g[3])), g[4]);
        float s = 0.f;
#pragma unroll
        for (int e = 0; e < 5; ++e) { g[e] = __expf(g[e] - mx); s += g[e]; }
        float inv = 1.f / s;
#pragma unroll
        for (int e = 0; e < 5; ++e) sWf[tid * 12 + e] = g[e] * inv;
    }

    // ---- G1: h = elu(hist @ vae_W1 + vae_b1), K=512; 32 cols/wave (2 nt) ----
    // (TA-minimal tiling: each weight fragment loaded exactly once per block.)
    f32x4 acc1[4][2];
#pragma unroll
    for (int nt = 0; nt < 2; ++nt) {
        f32x4 bi = *(const f32x4*)(vb1 + 32 * wv + 16 * nt + 4 * lg);
#pragma unroll
        for (int m = 0; m < 4; ++m) acc1[m][nt] = bi;
    }
    __builtin_amdgcn_s_setprio(1);
#pragma unroll
    for (int ks = 0; ks < 16; ++ks) {
        f16x8 wf[2];
#pragma unroll
        for (int nt = 0; nt < 2; ++nt)
            wf[nt] = *(const f16x8*)(W1T + (32 * wv + 16 * nt + lr) * 512 + 32 * ks + 8 * lg);
#pragma unroll
        for (int m = 0; m < 4; ++m) {
            f16x8 bf = *(const f16x8*)(sS2 + (16 * m + lr) * 488 + 32 * ks + 8 * lg);
#pragma unroll
            for (int nt = 0; nt < 2; ++nt)
                acc1[m][nt] = MFMA16(wf[nt], bf, acc1[m][nt]);
        }
    }
    __builtin_amdgcn_s_setprio(0);
    // prefetch o_t (99 cols of S2) into regs before S2 is overwritten
    const int r_ot = tid >> 3, sub = tid & 7;
    ushort_t otv[13];
#pragma unroll
    for (int i = 0; i < 13; ++i) {
        int j = sub + 8 * i;
        if (j < 99) {
            int s;
            if (j < 3) s = j;
            else if (j < 12) { int jj = j - 3; int t = jj / 3;
                               s = 15 * (t + 1) + (jj - 3 * t); }
            else { int jj = j - 12; int t2 = jj / 29;
                   s = 164 + 145 * t2 + (jj - 29 * t2); }
            otv[i] = __builtin_bit_cast(ushort_t, sS2[r_ot * 488 + s]);
        }
    }
    float we5[5];
    sync_lds();                                           // S7: S2 reads done

    // write h (elu); assemble B0
#pragma unroll
    for (int m = 0; m < 4; ++m)
#pragma unroll
        for (int nt = 0; nt < 2; ++nt)
            elu_store4(sH + (16 * m + lr) * 264 + 32 * wv + 16 * nt + 4 * lg, acc1[m][nt]);
#pragma unroll
    for (int i = 0; i < 13; ++i) {
        int j = sub + 8 * i;
        if (j < 99) sB0[r_ot * 200 + 5 + j] = __builtin_bit_cast(f16, otv[i]);
    }
    {
        char* b0r = (char*)sB0 + r_ot * 400;
        if (sub == 0) { *(uint2*)(b0r + 0) = (uint2){0u, 0u}; *(ushort_t*)(b0r + 8) = 0; }
        else if (sub == 1) { *(uint2*)(b0r + 280) = (uint2){0u, 0u}; }
        else if (sub == 2) { *(uint4*)(b0r + 352) = (uint4){0u,0u,0u,0u}; }
        else if (sub == 3) { *(uint4*)(b0r + 368) = (uint4){0u,0u,0u,0u}; }
    }
    {   // z_E -> B0 cols 144..175 (512 quads, 1 per thread)
        int r = tid >> 3, c4 = tid & 7;
        uint2 v = *(uint2*)((char*)sZE + r * 80 + 8 * c4);
        *(uint2*)((char*)sB0 + r * 400 + 288 + 8 * c4) = v;
    }
    const int mrow = wv & 3;        // L3 row-tile / we5 group
    const int nt3  = wv >> 2;       // L3 col-tile
#pragma unroll
    for (int e = 0; e < 5; ++e) we5[e] = sWf[(16 * mrow + lr) * 12 + e];
    sync_lds();                                           // S8

    // ---- G2: [v_pred|z_H] = h @ Wzv + bzv, K=256; waves 0..5 -> B0 ----
    if (wv < 6) {
        int c = wv >> 1, h = wv & 1;
        f32x4 bz = *(const f32x4*)(BZV + 16 * c + 4 * lg);
        f32x4 acc[2]; acc[0] = bz; acc[1] = bz;
#pragma unroll
        for (int ks = 0; ks < 8; ++ks) {
            f16x8 wf = *(const f16x8*)(WZV + (16 * c + lr) * 256 + 32 * ks + 8 * lg);
#pragma unroll
            for (int mm = 0; mm < 2; ++mm) {
                int m = 2 * h + mm;
                f16x8 bf = *(const f16x8*)(sH + (16 * m + lr) * 264 + 32 * ks + 8 * lg);
                acc[mm] = MFMA16(wf, bf, acc[mm]);
            }
        }
        if (c < 2 || lg == 0) {
            int col = (c < 2) ? (108 + 16 * c + 4 * lg) : 104;
#pragma unroll
            for (int mm = 0; mm < 2; ++mm)
                store4(sB0 + (16 * (2 * h + mm) + lr) * 200 + col, acc[mm]);
        }
    }
    sync_lds();                                           // S9

    // ---- experts: 5 x (L1 K=192, L2 K=128, L3 K=128); 16 cols/wave ----
    f32x4 oacc = (f32x4)0.f;

    for (int e = 0; e < 5; ++e) {
        // L1: h1 = elu(inp @ eW1 + eb1), col-tile = wv
        {
            f32x4 bi = *(const f32x4*)(eb1 + e * 128 + 16 * wv + 4 * lg);
            f32x4 acc[4];
#pragma unroll
            for (int m = 0; m < 4; ++m) acc[m] = bi;
            __builtin_amdgcn_s_setprio(1);
#pragma unroll
            for (int ks = 0; ks < 6; ++ks) {
                f16x8 wf = *(const f16x8*)(E1T + (e * 128 + 16 * wv + lr) * 192 + 32 * ks + 8 * lg);
#pragma unroll
                for (int m = 0; m < 4; ++m) {
                    f16x8 bf = *(const f16x8*)(sB0 + (16 * m + lr) * 200 + 32 * ks + 8 * lg);
                    acc[m] = MFMA16(wf, bf, acc[m]);
                }
            }
            __builtin_amdgcn_s_setprio(0);
#pragma unroll
            for (int m = 0; m < 4; ++m)
                elu_store4(sH1 + (16 * m + lr) * 136 + 16 * wv + 4 * lg, acc[m]);
        }
        sync_lds();
        // L2: h2 = elu(h1 @ eW2 + eb2), col-tile = wv
        {
            f32x4 bi = *(const f32x4*)(eb2 + e * 128 + 16 * wv + 4 * lg);
            f32x4 acc[4];
#pragma unroll
            for (int m = 0; m < 4; ++m) acc[m] = bi;
            __builtin_amdgcn_s_setprio(1);
#pragma unroll
            for (int ks = 0; ks < 4; ++ks) {
                f16x8 wf = *(const f16x8*)(E2T + (e * 128 + 16 * wv + lr) * 128 + 32 * ks + 8 * lg);
#pragma unroll
                for (int m = 0; m < 4; ++m) {
                    f16x8 bf = *(const f16x8*)(sH1 + (16 * m + lr) * 136 + 32 * ks + 8 * lg);
                    acc[m] = MFMA16(wf, bf, acc[m]);
                }
            }
            __builtin_amdgcn_s_setprio(0);
#pragma unroll
            for (int m = 0; m < 4; ++m)
                elu_store4(sH2 + (16 * m + lr) * 136 + 16 * wv + 4 * lg, acc[m]);
        }
        sync_lds();
        // L3: acts = h2 @ eW3 + eb3; rows 16*mrow, cols 16*nt3; weighted accumulate
        {
            f32x4 a3 = *(const f32x4*)(EB3P + e * 32 + 16 * nt3 + 4 * lg);
#pragma unroll
            for (int ks = 0; ks < 4; ++ks) {
                f16x8 bf = *(const f16x8*)(sH2 + (16 * mrow + lr) * 136 + 32 * ks + 8 * lg);
                f16x8 wf = *(const f16x8*)(E3T + (e * 32 + 16 * nt3 + lr) * 128 + 32 * ks + 8 * lg);
                a3 = MFMA16(wf, bf, a3);
            }
            float we = we5[e];
#pragma unroll
            for (int r = 0; r < 4; ++r) oacc[r] += we * a3[r];
        }
        sync_lds();
    }

    // ---- store out [64 x 29] fp32: row 16*mrow+lr, cols 16*nt3+4lg+r ----
    {
        int row = row0 + 16 * mrow + lr;
#pragma unroll
        for (int r = 0; r < 4; ++r) {
            int col = 16 * nt3 + 4 * lg + r;
            if (col < 29) out[(size_t)row * 29 + col] = oacc[r];
        }
    }
}

extern "C" void kernel_launch(void* const* d_in, const int* in_sizes, int n_in,
                              void* d_out, int out_size, void* d_ws, size_t ws_size,
                              hipStream_t stream)
{
    (void)n_in; (void)out_size; (void)ws_size;
    const float* x   = (const float*)d_in[0];
    const float* vW1 = (const float*)d_in[1];
    const float* vb1 = (const float*)d_in[2];
    const float* vWz = (const float*)d_in[3];
    const float* vbz = (const float*)d_in[4];
    const float* vWv = (const float*)d_in[5];
    const float* vbv = (const float*)d_in[6];
    const float* aW1 = (const float*)d_in[7];
    const float* ab1 = (const float*)d_in[8];
    const float* aW2 = (const float*)d_in[9];
    const float* ab2 = (const float*)d_in[10];
    const float* gW1 = (const float*)d_in[11];
    const float* gb1 = (const float*)d_in[12];
    const float* gW2 = (const float*)d_in[13];
    const float* gb2 = (const float*)d_in[14];
    const float* eW1 = (const float*)d_in[15];
    const float* eb1 = (const float*)d_in[16];
    const float* eW2 = (const float*)d_in[17];
    const float* eb2 = (const float*)d_in[18];
    const float* eW3 = (const float*)d_in[19];
    const float* eb3 = (const float*)d_in[20];

    int n = in_sizes[0] / 975;

    prep_kernel<<<(380128 + 255) / 256, 256, 0, stream>>>(
        vW1, vWz, vWv, aW1, aW2, gW1, gW2, eW1, eW2, eW3, vbz, vbv, eb3, gb2, (char*)d_ws);

    moe_fused<<<n / 64, 512, 0, stream>>>(
        x, vb1, ab1, ab2, gb1, eb1, eb2, (const char*)d_ws, (float*)d_out);
}

// Round 14
// 283.373 us; speedup vs baseline: 2.1545x; 1.0031x over previous
//
#include <hip/hip_runtime.h>
#include <math.h>

typedef _Float16 f16;
typedef f16  f16x8 __attribute__((ext_vector_type(8)));
typedef float f32x4 __attribute__((ext_vector_type(4)));
typedef float f32x4u __attribute__((ext_vector_type(4), aligned(4)));  // x rows are 4B-aligned
typedef unsigned short ushort_t;

#define MFMA16(a, b, c) __builtin_amdgcn_mfma_f32_16x16x32_f16((a), (b), (c), 0, 0, 0)

// ---------------- workspace layout (f16 element offsets) ----------------
#define W1T_E 0        // [256][512]  vae_W1^T, K permuted to S2 order
#define WZV_E 131072   // [48][256]   [vae_Wz | vae_Wv | 0]^T
#define A1T_E 143360   // [64][96]    ae_W1^T
#define A2T_E 149504   // [32][64]    ae_W2^T
#define G1T_E 151552   // [64][32]    gate_W1^T
#define G2T_E 153600   // [16][64]    gate_W2^T (cols 5..15 zero)
#define E1T_E 154624   // [5][128][192] eW1^T, K remapped to padded-192 buf0 layout
#define E2T_E 277504   // [5][128][128] eW2^T
#define E3T_E 359424   // [5][32][128]  eW3^T, cols 29..31 zero
#define F32_B 759808   // f32 appendix: BZV[48] | EB3P[160] | GB2P[16]

// ---------------- LDS layout (bytes), 64-row tile, 2 blocks/CU ----------------
#define S2_OFF   0       // [64][488] f16; alias: H[64][264]@0 + B0[64][200]@36864
#define B0_OFF   36864
#define H2_OFF   17408   // experts: H1@0, H2 here
#define ELEV_OFF 62528   // [64][104] f16 (64B zero pad at 62464); alias HA [64][72]
#define HA_OFF   62528
#define ZE_OFF   71744   // [64][40] f16
#define WF_OFF   76864   // [64][12] f32
#define SMEM_SZ  79936   // 2 x 79936 <= 163840 -> 2 blocks/CU (512 thr: 16 waves/CU)

__device__ __forceinline__ float elu_f(float v) {
    float e = __expf(v) - 1.f;
    return v > 0.f ? v : e;
}

// round-to-nearest f32x2 -> packed f16x2 (RTZ pkrtz biased the chain; keep RTN)
__device__ __forceinline__ unsigned pk(float a, float b) {
    ushort_t u0 = __builtin_bit_cast(ushort_t, (f16)a);
    ushort_t u1 = __builtin_bit_cast(ushort_t, (f16)b);
    return (unsigned)u0 | ((unsigned)u1 << 16);
}

__device__ __forceinline__ void store4(f16* p, f32x4 v) {
    uint2 t; t.x = pk(v[0], v[1]); t.y = pk(v[2], v[3]);
    *(uint2*)p = t;
}

__device__ __forceinline__ void elu_store4(f16* p, f32x4 v) {
    uint2 t; t.x = pk(elu_f(v[0]), elu_f(v[1])); t.y = pk(elu_f(v[2]), elu_f(v[3]));
    *(uint2*)p = t;
}

// LDS-only barrier: drains DS ops but leaves global loads in flight.
__device__ __forceinline__ void sync_lds() {
    asm volatile("s_waitcnt lgkmcnt(0)" ::: "memory");
    __builtin_amdgcn_s_barrier();
    asm volatile("" ::: "memory");
    __builtin_amdgcn_sched_barrier(0);
}

// ---------------- weight repack: fp32 -> f16, transposed/padded/permuted ----------------
__global__ void prep_kernel(const float* __restrict__ vW1, const float* __restrict__ vWz,
                            const float* __restrict__ vWv, const float* __restrict__ aW1,
                            const float* __restrict__ aW2, const float* __restrict__ gW1,
                            const float* __restrict__ gW2, const float* __restrict__ eW1,
                            const float* __restrict__ eW2, const float* __restrict__ eW3,
                            const float* __restrict__ vbz, const float* __restrict__ vbv,
                            const float* __restrict__ eb3, const float* __restrict__ gb2,
                            char* __restrict__ ws)
{
    int i = blockIdx.x * 256 + threadIdx.x;
    f16* H = (f16*)ws;
    if (i < 131072) {                                   // W1T [c=256][ks=512], S2-order K
        int c = i >> 9, ks = i & 511;
        int xcol = 12 + ks;
        float v = 0.f;
        if (xcol >= 15 && xcol <= 494) {
            int hc;
            if (xcol < 60) {
                int t = xcol / 15; int rm = xcol - 15 * t; int f = rm / 3;
                hc = 96 * f + 3 * (t - 1) + (rm - 3 * f);
            } else {
                int t2 = (xcol - 60) / 145; int rm = xcol - 60 - 145 * t2; int f = rm / 29;
                hc = 96 * f + 9 + 29 * t2 + (rm - 29 * f);
            }
            v = vW1[hc * 256 + c];
        }
        H[i] = (f16)v;
    } else if (i < 143360) {                            // WZV [c=48][k=256]
        int j = i - 131072; int c = j / 256, k = j - c * 256;
        float v = (c < 32) ? vWz[k * 32 + c] : ((c < 35) ? vWv[k * 3 + (c - 32)] : 0.f);
        H[i] = (f16)v;
    } else if (i < 149504) {                            // A1T [c=64][k=96]
        int j = i - 143360; int c = j / 96, k = j - c * 96;
        H[i] = (f16)aW1[k * 64 + c];
    } else if (i < 151552) {                            // A2T [c=32][k=64]
        int j = i - 149504; int c = j / 64, k = j - c * 64;
        H[i] = (f16)aW2[k * 32 + c];
    } else if (i < 153600) {                            // G1T [c=64][k=32]
        int j = i - 151552; int c = j / 32, k = j - c * 32;
        H[i] = (f16)gW1[k * 64 + c];
    } else if (i < 154624) {                            // G2T [c=16][k=64]
        int j = i - 153600; int c = j / 64, k = j - c * 64;
        H[i] = (f16)((c < 5) ? gW2[k * 5 + c] : 0.f);
    } else if (i < 277504) {                            // E1T [e][c=128][k=192] remapped
        int j = i - 154624; int e = j / 24576, jj = j - e * 24576;
        int c = jj / 192, k = jj - c * 192;
        int ko = (k >= 5 && k < 107)   ? (k - 5)
               : (k >= 108 && k < 140) ? (k - 6)
               : (k >= 144 && k < 176) ? (k - 10) : -1;
        H[i] = (f16)((ko >= 0) ? eW1[(e * 166 + ko) * 128 + c] : 0.f);
    } else if (i < 359424) {                            // E2T [e][c=128][k=128]
        int j = i - 277504; int e = j / 16384, jj = j - e * 16384;
        int c = jj / 128, k = jj - c * 128;
        H[i] = (f16)eW2[(e * 128 + k) * 128 + c];
    } else if (i < 379904) {                            // E3T [e][c=32][k=128]
        int j = i - 359424; int e = j / 4096, jj = j - e * 4096;
        int c = jj / 128, k = jj - c * 128;
        H[i] = (f16)((c < 29) ? eW3[(e * 128 + k) * 29 + c] : 0.f);
    } else if (i < 380128) {                            // f32 appendix
        int j = i - 379904;
        float* F = (float*)(ws + F32_B);
        float v;
        if (j < 48)       v = (j < 32) ? vbz[j] : ((j < 35) ? vbv[j - 32] : 0.f);
        else if (j < 208) { int t = j - 48; int e = t >> 5, c = t & 31;
                            v = (c < 29) ? eb3[e * 29 + c] : 0.f; }
        else              { int t = j - 208; v = (t < 5) ? gb2[t] : 0.f; }
        F[j] = v;
    }
}

// ---------------- fused actor: 64 rows/block, 512 threads ----------------
__global__ __launch_bounds__(512, 4) void moe_fused(
    const float* __restrict__ x,
    const float* __restrict__ vb1,
    const float* __restrict__ ab1,
    const float* __restrict__ ab2,
    const float* __restrict__ gb1,
    const float* __restrict__ eb1,
    const float* __restrict__ eb2,
    const char* __restrict__ ws,
    float* __restrict__ out)
{
    __shared__ __align__(16) char smem[SMEM_SZ];
    const int tid  = threadIdx.x;
    const int wv   = tid >> 6;      // 0..7
    const int lane = tid & 63;
    const int lr   = lane & 15;
    const int lg   = lane >> 4;
    const int rh   = wv & 1;        // row half for G3 (2 m-tiles)
    const int cq   = wv >> 1;       // col quarter 0..3
    const int row0 = (int)blockIdx.x * 64;

    const f16* W1T = (const f16*)ws + W1T_E;
    const f16* WZV = (const f16*)ws + WZV_E;
    const f16* A1T = (const f16*)ws + A1T_E;
    const f16* A2T = (const f16*)ws + A2T_E;
    const f16* G1T = (const f16*)ws + G1T_E;
    const f16* G2T = (const f16*)ws + G2T_E;
    const f16* E1T = (const f16*)ws + E1T_E;
    const f16* E2T = (const f16*)ws + E2T_E;
    const f16* E3T = (const f16*)ws + E3T_E;
    const float* BZV  = (const float*)(ws + F32_B);
    const float* EB3P = BZV + 48;
    const float* GB2P = BZV + 208;

    f16* sS2 = (f16*)(smem + S2_OFF);     // stride 488
    f16* sEl = (f16*)(smem + ELEV_OFF);   // stride 104
    f16* sHA = (f16*)(smem + HA_OFF);     // stride 72
    f16* sZE = (f16*)(smem + ZE_OFF);     // stride 40
    f16* sH  = (f16*)(smem + S2_OFF);     // stride 264 (after G1)
    f16* sB0 = (f16*)(smem + B0_OFF);     // stride 200
    f16* sH1 = (f16*)(smem + S2_OFF);     // stride 136 (experts)
    f16* sH2 = (f16*)(smem + H2_OFF);     // stride 136
    float* sWf = (float*)(smem + WF_OFF); // stride 12 f32

    // ---- P0: wide staging (R13: dwordx4 loads + b128 LDS writes) ----
    {
        if (tid < 16) *(unsigned*)(smem + 62464 + 4 * tid) = 0u;  // S2 tail pad
        const int sr0 = wv * 8;
#pragma unroll 2
        for (int rr = 0; rr < 8; ++rr) {
            const int r = sr0 + rr;
            const float* xr = x + (size_t)(row0 + r) * 975;
            if (lane < 61) {
                f32x4u a = *(const f32x4u*)(xr + 12 + 8 * lane);
                f32x4u b = *(const f32x4u*)(xr + 16 + 8 * lane);
                uint4 t; t.x = pk(a[0], a[1]); t.y = pk(a[2], a[3]);
                t.z = pk(b[0], b[1]); t.w = pk(b[2], b[3]);
                *(uint4*)(sS2 + r * 488 + 8 * lane) = t;
            }
            if (lane < 12) {
                f32x4u a = *(const f32x4u*)(xr + 879 + 8 * lane);
                f32x4u b = *(const f32x4u*)(xr + 883 + 8 * lane);
                uint4 t; t.x = pk(a[0], a[1]); t.y = pk(a[2], a[3]);
                t.z = pk(b[0], b[1]); t.w = pk(b[2], b[3]);
                *(uint4*)(sEl + r * 104 + 8 * lane) = t;
            }
        }
    }
    sync_lds();                                           // S1

    // ---- G3: ha = elu(e_t @ ae_W1 + ae_b1); 2 row-halves x 4 col-quarters ----
    f32x4 g3acc[2];
    {
        f32x4 bi = *(const f32x4*)(ab1 + 16 * cq + 4 * lg);
        g3acc[0] = bi; g3acc[1] = bi;
#pragma unroll
        for (int ks = 0; ks < 3; ++ks) {
            f16x8 wf = *(const f16x8*)(A1T + (16 * cq + lr) * 96 + 32 * ks + 8 * lg);
#pragma unroll
            for (int mm = 0; mm < 2; ++mm) {
                int m = 2 * rh + mm;
                f16x8 bf = *(const f16x8*)(sEl + (16 * m + lr) * 104 + 32 * ks + 8 * lg);
                g3acc[mm] = MFMA16(wf, bf, g3acc[mm]);
            }
        }
    }
    sync_lds();                                           // S2: elev reads done
#pragma unroll
    for (int mm = 0; mm < 2; ++mm)
        elu_store4(sHA + (16 * (2 * rh + mm) + lr) * 72 + 16 * cq + 4 * lg, g3acc[mm]);
    sync_lds();                                           // S3

    // ---- G4 (waves 0..3): z_E = ha @ ae_W2 + ae_b2 -> sZE ----
    if (wv < 4) {
        int c = wv >> 1, h = wv & 1;
        f32x4 bi = *(const f32x4*)(ab2 + 16 * c + 4 * lg);
        f32x4 acc[2]; acc[0] = bi; acc[1] = bi;
#pragma unroll
        for (int ks = 0; ks < 2; ++ks) {
            f16x8 wf = *(const f16x8*)(A2T + (16 * c + lr) * 64 + 32 * ks + 8 * lg);
#pragma unroll
            for (int mm = 0; mm < 2; ++mm) {
                int m = 2 * h + mm;
                f16x8 bf = *(const f16x8*)(sHA + (16 * m + lr) * 72 + 32 * ks + 8 * lg);
                acc[mm] = MFMA16(wf, bf, acc[mm]);
            }
        }
#pragma unroll
        for (int mm = 0; mm < 2; ++mm)
            store4(sZE + (16 * (2 * h + mm) + lr) * 40 + 16 * c + 4 * lg, acc[mm]);
    }
    sync_lds();                                           // S4

    // ---- gate hidden: gh = elu(z_E @ gate_W1 + gate_b1), K=32 -> sHA ----
    {
        f32x4 bi = *(const f32x4*)(gb1 + 16 * cq + 4 * lg);
        f32x4 acc[2]; acc[0] = bi; acc[1] = bi;
        f16x8 wf = *(const f16x8*)(G1T + (16 * cq + lr) * 32 + 8 * lg);
#pragma unroll
        for (int mm = 0; mm < 2; ++mm) {
            int m = 2 * rh + mm;
            f16x8 bf = *(const f16x8*)(sZE + (16 * m + lr) * 40 + 8 * lg);
            acc[mm] = MFMA16(wf, bf, acc[mm]);
        }
#pragma unroll
        for (int mm = 0; mm < 2; ++mm)
            elu_store4(sHA + (16 * (2 * rh + mm) + lr) * 72 + 16 * cq + 4 * lg, acc[mm]);
    }
    sync_lds();                                           // S5

    // ---- gate logits (wave 0) -> sWf; guarded (R2/R3 OOB lesson) ----
    if (wv == 0) {
        f32x4 bi = *(const f32x4*)(GB2P + 4 * lg);
        f32x4 acc[4];
#pragma unroll
        for (int m = 0; m < 4; ++m) acc[m] = bi;
#pragma unroll
        for (int ks = 0; ks < 2; ++ks) {
            f16x8 wf = *(const f16x8*)(G2T + lr * 64 + 32 * ks + 8 * lg);
#pragma unroll
            for (int m = 0; m < 4; ++m) {
                f16x8 bf = *(const f16x8*)(sHA + (16 * m + lr) * 72 + 32 * ks + 8 * lg);
                acc[m] = MFMA16(wf, bf, acc[m]);
            }
        }
        if (lg == 0) {
#pragma unroll
            for (int m = 0; m < 4; ++m)
                *(f32x4*)(sWf + (16 * m + lr) * 12) = acc[m];
        } else if (lg == 1) {
#pragma unroll
            for (int m = 0; m < 4; ++m)
                sWf[(16 * m + lr) * 12 + 4] = acc[m][0];
        }
    }
    sync_lds();                                           // S6

    // ---- softmax over 5 gate logits ----
    if (tid < 64) {
        float g[5];
#pragma unroll
        for (int e = 0; e < 5; ++e) g[e] = sWf[tid * 12 + e];
        float mx = fmaxf(fmaxf(fmaxf(g[0], g[1]), fmaxf(g[2], g[3])), g[4]);
        float s = 0.f;
#pragma unroll
        for (int e = 0; e < 5; ++e) { g[e] = __expf(g[e] - mx); s += g[e]; }
        float inv = 1.f / s;
#pragma unroll
        for (int e = 0; e < 5; ++e) sWf[tid * 12 + e] = g[e] * inv;
    }

    // ---- G1: h = elu(hist @ vae_W1 + vae_b1), K=512; 32 cols/wave (2 nt) ----
    f32x4 acc1[4][2];
#pragma unroll
    for (int nt = 0; nt < 2; ++nt) {
        f32x4 bi = *(const f32x4*)(vb1 + 32 * wv + 16 * nt + 4 * lg);
#pragma unroll
        for (int m = 0; m < 4; ++m) acc1[m][nt] = bi;
    }
    __builtin_amdgcn_s_setprio(1);
#pragma unroll
    for (int ks = 0; ks < 16; ++ks) {
        f16x8 wf[2];
#pragma unroll
        for (int nt = 0; nt < 2; ++nt)
            wf[nt] = *(const f16x8*)(W1T + (32 * wv + 16 * nt + lr) * 512 + 32 * ks + 8 * lg);
#pragma unroll
        for (int m = 0; m < 4; ++m) {
            f16x8 bf = *(const f16x8*)(sS2 + (16 * m + lr) * 488 + 32 * ks + 8 * lg);
#pragma unroll
            for (int nt = 0; nt < 2; ++nt)
                acc1[m][nt] = MFMA16(wf[nt], bf, acc1[m][nt]);
        }
    }
    __builtin_amdgcn_s_setprio(0);
    // prefetch o_t (99 cols of S2) into regs before S2 is overwritten
    const int r_ot = tid >> 3, sub = tid & 7;
    ushort_t otv[13];
#pragma unroll
    for (int i = 0; i < 13; ++i) {
        int j = sub + 8 * i;
        if (j < 99) {
            int s;
            if (j < 3) s = j;
            else if (j < 12) { int jj = j - 3; int t = jj / 3;
                               s = 15 * (t + 1) + (jj - 3 * t); }
            else { int jj = j - 12; int t2 = jj / 29;
                   s = 164 + 145 * t2 + (jj - 29 * t2); }
            otv[i] = __builtin_bit_cast(ushort_t, sS2[r_ot * 488 + s]);
        }
    }
    float we5[5];
    sync_lds();                                           // S7: S2 reads done

    // write h (elu); assemble B0
#pragma unroll
    for (int m = 0; m < 4; ++m)
#pragma unroll
        for (int nt = 0; nt < 2; ++nt)
            elu_store4(sH + (16 * m + lr) * 264 + 32 * wv + 16 * nt + 4 * lg, acc1[m][nt]);
#pragma unroll
    for (int i = 0; i < 13; ++i) {
        int j = sub + 8 * i;
        if (j < 99) sB0[r_ot * 200 + 5 + j] = __builtin_bit_cast(f16, otv[i]);
    }
    {
        char* b0r = (char*)sB0 + r_ot * 400;
        if (sub == 0) { *(uint2*)(b0r + 0) = (uint2){0u, 0u}; *(ushort_t*)(b0r + 8) = 0; }
        else if (sub == 1) { *(uint2*)(b0r + 280) = (uint2){0u, 0u}; }
        else if (sub == 2) { *(uint4*)(b0r + 352) = (uint4){0u,0u,0u,0u}; }
        else if (sub == 3) { *(uint4*)(b0r + 368) = (uint4){0u,0u,0u,0u}; }
    }
    {   // z_E -> B0 cols 144..175 (512 quads, 1 per thread)
        int r = tid >> 3, c4 = tid & 7;
        uint2 v = *(uint2*)((char*)sZE + r * 80 + 8 * c4);
        *(uint2*)((char*)sB0 + r * 400 + 288 + 8 * c4) = v;
    }
    const int mrow = wv & 3;        // L3 row-tile / we5 group
    const int nt3  = wv >> 2;       // L3 col-tile
#pragma unroll
    for (int e = 0; e < 5; ++e) we5[e] = sWf[(16 * mrow + lr) * 12 + e];
    sync_lds();                                           // S8

    // ---- G2: [v_pred|z_H] = h @ Wzv + bzv, K=256; waves 0..5 -> B0 ----
    if (wv < 6) {
        int c = wv >> 1, h = wv & 1;
        f32x4 bz = *(const f32x4*)(BZV + 16 * c + 4 * lg);
        f32x4 acc[2]; acc[0] = bz; acc[1] = bz;
#pragma unroll
        for (int ks = 0; ks < 8; ++ks) {
            f16x8 wf = *(const f16x8*)(WZV + (16 * c + lr) * 256 + 32 * ks + 8 * lg);
#pragma unroll
            for (int mm = 0; mm < 2; ++mm) {
                int m = 2 * h + mm;
                f16x8 bf = *(const f16x8*)(sH + (16 * m + lr) * 264 + 32 * ks + 8 * lg);
                acc[mm] = MFMA16(wf, bf, acc[mm]);
            }
        }
        if (c < 2 || lg == 0) {
            int col = (c < 2) ? (108 + 16 * c + 4 * lg) : 104;
#pragma unroll
            for (int mm = 0; mm < 2; ++mm)
                store4(sB0 + (16 * (2 * h + mm) + lr) * 200 + col, acc[mm]);
        }
    }
    sync_lds();                                           // S9

    // ---- experts: L3(e-1) folded into L1(e) phase -> 2 barriers/expert ----
    // Hazards: L3(e-1) reads H2 (written in L2(e-1), barrier-separated); next
    // H2 write is L2(e), separated by the L1-phase-end barrier. L1(e) writes H1
    // only after L2(e-1) finished reading it (previous barrier).
    f32x4 oacc = (f32x4)0.f;

    for (int e = 0; e < 5; ++e) {
        // phase A: L1(e) + folded L3(e-1)
        {
            f32x4 bi = *(const f32x4*)(eb1 + e * 128 + 16 * wv + 4 * lg);
            f32x4 acc[4];
#pragma unroll
            for (int m = 0; m < 4; ++m) acc[m] = bi;
            __builtin_amdgcn_s_setprio(1);
#pragma unroll
            for (int ks = 0; ks < 6; ++ks) {
                f16x8 wf = *(const f16x8*)(E1T + (e * 128 + 16 * wv + lr) * 192 + 32 * ks + 8 * lg);
#pragma unroll
                for (int m = 0; m < 4; ++m) {
                    f16x8 bf = *(const f16x8*)(sB0 + (16 * m + lr) * 200 + 32 * ks + 8 * lg);
                    acc[m] = MFMA16(wf, bf, acc[m]);
                }
            }
            if (e > 0) {   // L3(e-1): rows 16*mrow, cols 16*nt3, reads H2
                f32x4 a3 = *(const f32x4*)(EB3P + (e - 1) * 32 + 16 * nt3 + 4 * lg);
#pragma unroll
                for (int ks = 0; ks < 4; ++ks) {
                    f16x8 bf = *(const f16x8*)(sH2 + (16 * mrow + lr) * 136 + 32 * ks + 8 * lg);
                    f16x8 wf = *(const f16x8*)(E3T + ((e - 1) * 32 + 16 * nt3 + lr) * 128 + 32 * ks + 8 * lg);
                    a3 = MFMA16(wf, bf, a3);
                }
                float we = we5[e - 1];
#pragma unroll
                for (int r = 0; r < 4; ++r) oacc[r] += we * a3[r];
            }
            __builtin_amdgcn_s_setprio(0);
#pragma unroll
            for (int m = 0; m < 4; ++m)
                elu_store4(sH1 + (16 * m + lr) * 136 + 16 * wv + 4 * lg, acc[m]);
        }
        sync_lds();
        // phase B: L2(e)
        {
            f32x4 bi = *(const f32x4*)(eb2 + e * 128 + 16 * wv + 4 * lg);
            f32x4 acc[4];
#pragma unroll
            for (int m = 0; m < 4; ++m) acc[m] = bi;
            __builtin_amdgcn_s_setprio(1);
#pragma unroll
            for (int ks = 0; ks < 4; ++ks) {
                f16x8 wf = *(const f16x8*)(E2T + (e * 128 + 16 * wv + lr) * 128 + 32 * ks + 8 * lg);
#pragma unroll
                for (int m = 0; m < 4; ++m) {
                    f16x8 bf = *(const f16x8*)(sH1 + (16 * m + lr) * 136 + 32 * ks + 8 * lg);
                    acc[m] = MFMA16(wf, bf, acc[m]);
                }
            }
            __builtin_amdgcn_s_setprio(0);
#pragma unroll
            for (int m = 0; m < 4; ++m)
                elu_store4(sH2 + (16 * m + lr) * 136 + 16 * wv + 4 * lg, acc[m]);
        }
        sync_lds();
    }
    // final L3(4): H2 just written + barrier above
    {
        f32x4 a3 = *(const f32x4*)(EB3P + 4 * 32 + 16 * nt3 + 4 * lg);
#pragma unroll
        for (int ks = 0; ks < 4; ++ks) {
            f16x8 bf = *(const f16x8*)(sH2 + (16 * mrow + lr) * 136 + 32 * ks + 8 * lg);
            f16x8 wf = *(const f16x8*)(E3T + (4 * 32 + 16 * nt3 + lr) * 128 + 32 * ks + 8 * lg);
            a3 = MFMA16(wf, bf, a3);
        }
        float we = we5[4];
#pragma unroll
        for (int r = 0; r < 4; ++r) oacc[r] += we * a3[r];
    }

    // ---- store out [64 x 29] fp32: row 16*mrow+lr, cols 16*nt3+4lg+r ----
    {
        int row = row0 + 16 * mrow + lr;
#pragma unroll
        for (int r = 0; r < 4; ++r) {
            int col = 16 * nt3 + 4 * lg + r;
            if (col < 29) out[(size_t)row * 29 + col] = oacc[r];
        }
    }
}

extern "C" void kernel_launch(void* const* d_in, const int* in_sizes, int n_in,
                              void* d_out, int out_size, void* d_ws, size_t ws_size,
                              hipStream_t stream)
{
    (void)n_in; (void)out_size; (void)ws_size;
    const float* x   = (const float*)d_in[0];
    const float* vW1 = (const float*)d_in[1];
    const float* vb1 = (const float*)d_in[2];
    const float* vWz = (const float*)d_in[3];
    const float* vbz = (const float*)d_in[4];
    const float* vWv = (const float*)d_in[5];
    const float* vbv = (const float*)d_in[6];
    const float* aW1 = (const float*)d_in[7];
    const float* ab1 = (const float*)d_in[8];
    const float* aW2 = (const float*)d_in[9];
    const float* ab2 = (const float*)d_in[10];
    const float* gW1 = (const float*)d_in[11];
    const float* gb1 = (const float*)d_in[12];
    const float* gW2 = (const float*)d_in[13];
    const float* gb2 = (const float*)d_in[14];
    const float* eW1 = (const float*)d_in[15];
    const float* eb1 = (const float*)d_in[16];
    const float* eW2 = (const float*)d_in[17];
    const float* eb2 = (const float*)d_in[18];
    const float* eW3 = (const float*)d_in[19];
    const float* eb3 = (const float*)d_in[20];

    int n = in_sizes[0] / 975;

    prep_kernel<<<(380128 + 255) / 256, 256, 0, stream>>>(
        vW1, vWz, vWv, aW1, aW2, gW1, gW2, eW1, eW2, eW3, vbz, vbv, eb3, gb2, (char*)d_ws);

    moe_fused<<<n / 64, 512, 0, stream>>>(
        x, vb1, ab1, ab2, gb1, eb1, eb2, (const char*)d_ws, (float*)d_out);
}